// Round 3
// baseline (2384.931 us; speedup 1.0000x reference)
//
#include <hip/hip_runtime.h>
#include <cstdint>
#include <cstddef>

// HGT layer: N=100000 nodes, E=400000 edges/relation, D=256, H=8, DK=32, R=2.
// f32 baseline, workspace-slimmed (round 2): total d_ws usage 327.7 MB;
// AGG lives in d_out (exactly out_size); MU/DEN reused across relations;
// no hipMemset* (zero-fill kernels instead, graph-capture-safe by construction).
//
//   1. build_B: fold rel_att/rel_msg 32x32 head transforms into projection
//      weights -> fused B [256][1280] = [Wq | Wk@att0 | Wv@msg0 | Wk@att1 | Wv@msg1].
//   2. gemm_bias (f32 SGEMM, 128x128 tile, 8x8 microtile): QKV [N][768] = q|kr|vr.
//   3. Per relation: score (wave/edge dot + ordered-uint atomicMax segment max),
//      expsum (exp + atomicAdd segment sum), agg (atomicAdd weighted V into d_out).
//   4. Output projection GEMM (alpha=0.5 cross-relation mean) + residual LN.

#define NN 100000
#define EE 400000

static constexpr float INV_SQRT_DK = 0.17677669529663687f; // 1/sqrt(32)

// ---------------- workspace layout (float offsets), total 81,928,960 f = 327.7 MB ----
static constexpr size_t OFF_QKV  = 0;                                   // [N][768] q|kr|vr
static constexpr size_t OFF_SC   = OFF_QKV + (size_t)NN * 768;          // [E][8] score -> ex
static constexpr size_t OFF_MU   = OFF_SC  + (size_t)EE * 8;            // [N][8] ordered-uint max
static constexpr size_t OFF_DEN  = OFF_MU  + (size_t)NN * 8;            // [N][8]
static constexpr size_t OFF_B    = OFF_DEN + (size_t)NN * 8;            // [256][1280]
static constexpr size_t OFF_BIAS = OFF_B   + (size_t)256 * 1280;        // [1280]
static constexpr size_t WS_FLOATS = OFF_BIAS + 1280;

// ---------------- zero fill ----------------
__global__ __launch_bounds__(256)
void zero_kernel(float4* __restrict__ p, long n4)
{
    const long stride = (long)gridDim.x * blockDim.x;
    for (long i = (long)blockIdx.x * blockDim.x + threadIdx.x; i < n4; i += stride)
        p[i] = make_float4(0.f, 0.f, 0.f, 0.f);
}

// ---------------- fused weight build ----------------
__global__ __launch_bounds__(256)
void build_B_kernel(const float* __restrict__ Wk, const float* __restrict__ Wq,
                    const float* __restrict__ Wv,
                    const float* __restrict__ bk, const float* __restrict__ bq,
                    const float* __restrict__ bv,
                    const float* __restrict__ rel_att, const float* __restrict__ rel_msg,
                    float* __restrict__ Bbuf, float* __restrict__ biasbuf)
{
    const int din = blockIdx.x;   // 0..255 (input dim)
    const int t   = threadIdx.x;  // 0..255 (output col within segment)
    __shared__ float wk[256], wv[256];
    wk[t] = Wk[din * 256 + t];
    wv[t] = Wv[din * 256 + t];
    __syncthreads();
    const int h = t >> 5, e = t & 31;
    // segment 0: plain Wq
    Bbuf[(size_t)din * 1280 + t] = Wq[din * 256 + t];
    #pragma unroll
    for (int r = 0; r < 2; ++r) {
        const float* ra = rel_att + (size_t)((r * 8 + h) * 32) * 32 + e; // stride 32 over d
        const float* rm = rel_msg + (size_t)((r * 8 + h) * 32) * 32 + e;
        float sa = 0.f, sm = 0.f;
        #pragma unroll
        for (int dd = 0; dd < 32; ++dd) {
            sa = fmaf(wk[h * 32 + dd], ra[dd * 32], sa);
            sm = fmaf(wv[h * 32 + dd], rm[dd * 32], sm);
        }
        Bbuf[(size_t)din * 1280 + 256 + r * 512 + t]       = sa;
        Bbuf[(size_t)din * 1280 + 256 + r * 512 + 256 + t] = sm;
    }
    if (din == 0) {
        biasbuf[t] = bq[t];
        #pragma unroll
        for (int r = 0; r < 2; ++r) {
            float sa = 0.f, sm = 0.f;
            #pragma unroll
            for (int dd = 0; dd < 32; ++dd) {
                sa = fmaf(bk[h * 32 + dd], rel_att[(size_t)((r * 8 + h) * 32 + dd) * 32 + e], sa);
                sm = fmaf(bv[h * 32 + dd], rel_msg[(size_t)((r * 8 + h) * 32 + dd) * 32 + e], sm);
            }
            biasbuf[256 + r * 512 + t]       = sa;
            biasbuf[256 + r * 512 + 256 + t] = sm;
        }
    }
}

// ---------------- tiled f32 GEMM: C = alpha*(A@B) + bias ----------------
// 128x128 tile, TK=16, 256 threads, 8x8 microtile per thread.
#define TM 128
#define TN 128
#define TK 16

__global__ __launch_bounds__(256)
void gemm_bias(const float* __restrict__ A, int lda,
               const float* __restrict__ B, int ldb,
               const float* __restrict__ bias,
               float* __restrict__ C, int ldc,
               int M, int K, int Nc, float alpha)
{
    __shared__ float As[TK][TM]; // stored transposed: As[k][m]
    __shared__ float Bs[TK][TN];
    const int tid = threadIdx.x;
    const int bm = blockIdx.x * TM;
    const int bn = blockIdx.y * TN;
    const int tr = tid >> 4;   // 0..15 -> 8 rows each
    const int tc = tid & 15;   // 0..15 -> 2x4 cols each
    float acc[8][8];
    #pragma unroll
    for (int i = 0; i < 8; ++i)
        #pragma unroll
        for (int j = 0; j < 8; ++j) acc[i][j] = 0.f;

    for (int k0 = 0; k0 < K; k0 += TK) {
        // A tile: 128 rows x 16 k = 512 float4 slots, 2 per thread (lane-coalesced)
        #pragma unroll
        for (int i = 0; i < 2; ++i) {
            int s = tid + i * 256;      // 0..511
            int row = s >> 2;           // 0..127
            int c4 = (s & 3) << 2;      // 0,4,8,12
            float4 av = make_float4(0.f, 0.f, 0.f, 0.f);
            if (bm + row < M)
                av = *reinterpret_cast<const float4*>(A + (size_t)(bm + row) * lda + k0 + c4);
            As[c4 + 0][row] = av.x;
            As[c4 + 1][row] = av.y;
            As[c4 + 2][row] = av.z;
            As[c4 + 3][row] = av.w;
        }
        // B tile: 16 k x 128 cols = 512 float4 slots, 2 per thread (lane-coalesced)
        #pragma unroll
        for (int i = 0; i < 2; ++i) {
            int s = tid + i * 256;      // 0..511
            int brow = s >> 5;          // 0..15
            int bc = (s & 31) << 2;     // 0..124
            float4 bv = *reinterpret_cast<const float4*>(B + (size_t)(k0 + brow) * ldb + bn + bc);
            *reinterpret_cast<float4*>(&Bs[brow][bc]) = bv;
        }
        __syncthreads();
        #pragma unroll
        for (int kk = 0; kk < TK; ++kk) {
            float4 a0 = *reinterpret_cast<const float4*>(&As[kk][tr * 8]);
            float4 a1 = *reinterpret_cast<const float4*>(&As[kk][tr * 8 + 4]);
            float4 b0 = *reinterpret_cast<const float4*>(&Bs[kk][tc * 4]);
            float4 b1 = *reinterpret_cast<const float4*>(&Bs[kk][tc * 4 + 64]);
            float a[8] = {a0.x, a0.y, a0.z, a0.w, a1.x, a1.y, a1.z, a1.w};
            float b[8] = {b0.x, b0.y, b0.z, b0.w, b1.x, b1.y, b1.z, b1.w};
            #pragma unroll
            for (int i = 0; i < 8; ++i)
                #pragma unroll
                for (int j = 0; j < 8; ++j)
                    acc[i][j] = fmaf(a[i], b[j], acc[i][j]);
        }
        __syncthreads();
    }
    #pragma unroll
    for (int i = 0; i < 8; ++i) {
        int row = bm + tr * 8 + i;
        if (row < M) {
            int col0 = bn + tc * 4;
            int col1 = bn + tc * 4 + 64;
            float4 o0, o1;
            o0.x = alpha * acc[i][0] + bias[col0 + 0];
            o0.y = alpha * acc[i][1] + bias[col0 + 1];
            o0.z = alpha * acc[i][2] + bias[col0 + 2];
            o0.w = alpha * acc[i][3] + bias[col0 + 3];
            o1.x = alpha * acc[i][4] + bias[col1 + 0];
            o1.y = alpha * acc[i][5] + bias[col1 + 1];
            o1.z = alpha * acc[i][6] + bias[col1 + 2];
            o1.w = alpha * acc[i][7] + bias[col1 + 3];
            *reinterpret_cast<float4*>(C + (size_t)row * ldc + col0) = o0;
            *reinterpret_cast<float4*>(C + (size_t)row * ldc + col1) = o1;
        }
    }
}

// ---------------- per-edge score + segment max ----------------
__global__ __launch_bounds__(256)
void score_kernel(const float* __restrict__ QKV,
                  const int* __restrict__ src, const int* __restrict__ dst,
                  const float* __restrict__ pri,   // [8]
                  float* __restrict__ sc,          // [E][8]
                  unsigned int* __restrict__ mu,   // [N][8], init 0
                  int E)
{
    const int gtid = blockIdx.x * blockDim.x + threadIdx.x;
    const int wid = gtid >> 6;
    const int nw = (gridDim.x * blockDim.x) >> 6;
    const int half = (threadIdx.x >> 5) & 1;
    const int d = threadIdx.x & 31;
    for (int e = wid; e < E; e += nw) {
        const int s = src[e];
        const int t = dst[e];
        const float* qrow = QKV + (size_t)t * 768;        // q
        const float* krow = QKV + (size_t)s * 768 + 256;  // kr
        #pragma unroll
        for (int hh = 0; hh < 4; ++hh) {
            const int hidx = hh * 2 + half;
            const int hd = hidx * 32 + d;
            float p = qrow[hd] * krow[hd];
            #pragma unroll
            for (int off = 16; off; off >>= 1)
                p += __shfl_xor(p, off, 32);
            if (d == 0) {
                float scv = p * pri[hidx] * INV_SQRT_DK;
                sc[(size_t)e * 8 + hidx] = scv;
                unsigned int bbits = __float_as_uint(scv);
                unsigned int ord = bbits ^ ((bbits & 0x80000000u) ? 0xFFFFFFFFu : 0x80000000u);
                atomicMax(&mu[(size_t)t * 8 + hidx], ord);
            }
        }
    }
}

// ---------------- exp + segment sum ----------------
__global__ __launch_bounds__(256)
void expsum_kernel(const int* __restrict__ dst,
                   const unsigned int* __restrict__ mu,
                   float* __restrict__ sc, float* __restrict__ den, int E)
{
    const int stride = gridDim.x * blockDim.x;
    const int total = E * 8;
    for (int i = blockIdx.x * blockDim.x + threadIdx.x; i < total; i += stride) {
        const int e = i >> 3, hidx = i & 7;
        const int t = dst[e];
        unsigned int u = mu[(size_t)t * 8 + hidx];
        float m = (u & 0x80000000u) ? __uint_as_float(u ^ 0x80000000u)
                                    : __uint_as_float(~u);
        float ex = __expf(sc[i] - m);
        sc[i] = ex;
        atomicAdd(&den[(size_t)t * 8 + hidx], ex);
    }
}

// ---------------- weighted V aggregation (into d_out as scratch) ----------------
__global__ __launch_bounds__(256)
void agg_kernel(const float* __restrict__ QKV,
                const int* __restrict__ src, const int* __restrict__ dst,
                const float* __restrict__ sc, const float* __restrict__ den,
                float* __restrict__ agg, int E)
{
    const int gtid = blockIdx.x * blockDim.x + threadIdx.x;
    const int wid = gtid >> 6;
    const int nw = (gridDim.x * blockDim.x) >> 6;
    const int half = (threadIdx.x >> 5) & 1;
    const int d = threadIdx.x & 31;
    for (int e = wid; e < E; e += nw) {
        const int s = src[e];
        const int t = dst[e];
        const float* vrow = QKV + (size_t)s * 768 + 512;  // vr
        #pragma unroll
        for (int hh = 0; hh < 4; ++hh) {
            const int hidx = hh * 2 + half;
            const float w = sc[(size_t)e * 8 + hidx] / den[(size_t)t * 8 + hidx];
            atomicAdd(&agg[(size_t)t * 256 + hidx * 32 + d], vrow[hidx * 32 + d] * w);
        }
    }
}

// ---------------- residual + LayerNorm ----------------
__global__ __launch_bounds__(256)
void ln_kernel(const float* __restrict__ tmp, const float* __restrict__ hres,
               const float* __restrict__ g, const float* __restrict__ b,
               float* __restrict__ out, int M)
{
    const int gtid = blockIdx.x * blockDim.x + threadIdx.x;
    const int wid = gtid >> 6;
    const int nw = (gridDim.x * blockDim.x) >> 6;
    const int lane = threadIdx.x & 63;
    const float4 gv = reinterpret_cast<const float4*>(g)[lane];
    const float4 bv = reinterpret_cast<const float4*>(b)[lane];
    for (int row = wid; row < M; row += nw) {
        const float4 tv = reinterpret_cast<const float4*>(tmp + (size_t)row * 256)[lane];
        const float4 hv = reinterpret_cast<const float4*>(hres + (size_t)row * 256)[lane];
        float y0 = tv.x + hv.x, y1 = tv.y + hv.y, y2 = tv.z + hv.z, y3 = tv.w + hv.w;
        float ssum = y0 + y1 + y2 + y3;
        #pragma unroll
        for (int off = 32; off; off >>= 1) ssum += __shfl_xor(ssum, off, 64);
        const float mean = ssum * (1.f / 256.f);
        const float d0 = y0 - mean, d1 = y1 - mean, d2 = y2 - mean, d3 = y3 - mean;
        float sq = d0 * d0 + d1 * d1 + d2 * d2 + d3 * d3;
        #pragma unroll
        for (int off = 32; off; off >>= 1) sq += __shfl_xor(sq, off, 64);
        const float inv = rsqrtf(sq * (1.f / 256.f) + 1e-5f);
        float4 o;
        o.x = d0 * inv * gv.x + bv.x;
        o.y = d1 * inv * gv.y + bv.y;
        o.z = d2 * inv * gv.z + bv.z;
        o.w = d3 * inv * gv.w + bv.w;
        reinterpret_cast<float4*>(out + (size_t)row * 256)[lane] = o;
    }
}

extern "C" void kernel_launch(void* const* d_in, const int* in_sizes, int n_in,
                              void* d_out, int out_size, void* d_ws, size_t ws_size,
                              hipStream_t stream)
{
    const float* h    = (const float*)d_in[0];
    const int* src0   = (const int*)d_in[1];
    const int* dst0   = (const int*)d_in[2];
    const int* src1   = (const int*)d_in[3];
    const int* dst1   = (const int*)d_in[4];
    const float* Wk   = (const float*)d_in[5];
    const float* bk   = (const float*)d_in[6];
    const float* Wq   = (const float*)d_in[7];
    const float* bq   = (const float*)d_in[8];
    const float* Wv   = (const float*)d_in[9];
    const float* bv   = (const float*)d_in[10];
    const float* Wa   = (const float*)d_in[11];
    const float* ba   = (const float*)d_in[12];
    const float* lng  = (const float*)d_in[13];
    const float* lnb  = (const float*)d_in[14];
    const float* rel_pri = (const float*)d_in[15];
    const float* rel_att = (const float*)d_in[16];
    const float* rel_msg = (const float*)d_in[17];

    float* ws   = (float*)d_ws;
    float* QKV  = ws + OFF_QKV;
    float* SC   = ws + OFF_SC;
    unsigned int* MU = (unsigned int*)(ws + OFF_MU);
    float* DEN  = ws + OFF_DEN;
    float* BBUF = ws + OFF_B;
    float* BIAS = ws + OFF_BIAS;
    float* AGG  = (float*)d_out;   // [N][256] == out_size; scratch until final LN

    // zero AGG (d_out) and MU/DEN (contiguous) — kernels, not memset
    zero_kernel<<<2048, 256, 0, stream>>>((float4*)AGG, (long)NN * 256 / 4);
    zero_kernel<<<512, 256, 0, stream>>>((float4*)(ws + OFF_MU), (long)NN * 16 / 4);

    // fused weights
    build_B_kernel<<<256, 256, 0, stream>>>(Wk, Wq, Wv, bk, bq, bv,
                                            rel_att, rel_msg, BBUF, BIAS);

    // GEMM1: [N,256] x [256,768] -> q | kr0 | vr0
    {
        dim3 grid((NN + TM - 1) / TM, 768 / TN);
        gemm_bias<<<grid, 256, 0, stream>>>(h, 256, BBUF, 1280, BIAS,
                                            QKV, 768, NN, 256, 768, 1.0f);
    }
    // relation 0
    score_kernel<<<4096, 256, 0, stream>>>(QKV, src0, dst0, rel_pri + 0, SC, MU, EE);
    expsum_kernel<<<2048, 256, 0, stream>>>(dst0, MU, SC, DEN, EE);
    agg_kernel<<<4096, 256, 0, stream>>>(QKV, src0, dst0, SC, DEN, AGG, EE);

    // reset MU/DEN for relation 1
    zero_kernel<<<512, 256, 0, stream>>>((float4*)(ws + OFF_MU), (long)NN * 16 / 4);

    // GEMM2: [N,256] x [256,512] -> kr1 | vr1 (overwrites kr0|vr0 region, q kept)
    {
        dim3 grid((NN + TM - 1) / TM, 512 / TN);
        gemm_bias<<<grid, 256, 0, stream>>>(h, 256, BBUF + 768, 1280, BIAS + 768,
                                            QKV + 256, 768, NN, 256, 512, 1.0f);
    }
    // relation 1
    score_kernel<<<4096, 256, 0, stream>>>(QKV, src1, dst1, rel_pri + 8, SC, MU, EE);
    expsum_kernel<<<2048, 256, 0, stream>>>(dst1, MU, SC, DEN, EE);
    agg_kernel<<<4096, 256, 0, stream>>>(QKV, src1, dst1, SC, DEN, AGG, EE);

    // output projection: tmp = 0.5*(agg @ Wa) + ba   (tmp aliases dead QKV region)
    float* TMP = ws + OFF_QKV;
    {
        dim3 grid((NN + TM - 1) / TM, 256 / TN);
        gemm_bias<<<grid, 256, 0, stream>>>(AGG, 256, Wa, 256, ba,
                                            TMP, 256, NN, 256, 256, 0.5f);
    }
    // residual + layernorm (reads TMP, overwrites d_out)
    ln_kernel<<<2048, 256, 0, stream>>>(TMP, h, lng, lnb, (float*)d_out, NN);
}

// Round 4
// 1900.310 us; speedup vs baseline: 1.2550x; 1.2550x over previous
//
#include <hip/hip_runtime.h>
#include <cstdint>
#include <cstddef>

// HGT layer: N=100000 nodes, E=400000 edges/relation, D=256, H=8, DK=32, R=2.
// Round 3: edge phase restructured to CSR + fused online-softmax aggregation.
//   1. build_B: fold rel_att/rel_msg 32x32 head transforms into projection
//      weights -> fused B [256][1280] = [Wq | Wk@att0 | Wv@msg0 | Wk@att1 | Wv@msg1].
//   2. gemm_bias (f32 SGEMM, 128x128 tile, 8x8 microtile): QKV [N][768] = q|kr|vr.
//   3. Per relation: CSR build (hist -> scan -> scatter), then node_agg:
//      one wave per dst node, online softmax over incoming edges, kr/vr row
//      gathers, single non-atomic 1KB write per node into AGG (d_out scratch).
//   4. Output projection GEMM (alpha=0.5 cross-relation mean) + residual LN.

#define NN 100000
#define EE 400000

static constexpr float INV_SQRT_DK = 0.17677669529663687f; // 1/sqrt(32)

// ---------------- workspace layout (float offsets), total ~311.3 MB ----------------
static constexpr size_t OFF_QKV    = 0;                                  // [N][768] q|kr|vr
static constexpr size_t OFF_B      = OFF_QKV    + (size_t)NN * 768;      // [256][1280]
static constexpr size_t OFF_BIAS   = OFF_B      + (size_t)256 * 1280;    // [1280]
static constexpr size_t OFF_DEG    = OFF_BIAS   + 1280;                  // [N] int
static constexpr size_t OFF_ROWPTR = OFF_DEG    + NN;                    // [N] int
static constexpr size_t OFF_CURSOR = OFF_ROWPTR + NN;                    // [N] int
static constexpr size_t OFF_SRCS   = OFF_CURSOR + NN;                    // [E] int
static constexpr size_t WS_FLOATS  = OFF_SRCS   + EE;

// ---------------- zero fill ----------------
__global__ __launch_bounds__(256)
void zero_kernel(float4* __restrict__ p, long n4)
{
    const long stride = (long)gridDim.x * blockDim.x;
    for (long i = (long)blockIdx.x * blockDim.x + threadIdx.x; i < n4; i += stride)
        p[i] = make_float4(0.f, 0.f, 0.f, 0.f);
}

// ---------------- fused weight build ----------------
__global__ __launch_bounds__(256)
void build_B_kernel(const float* __restrict__ Wk, const float* __restrict__ Wq,
                    const float* __restrict__ Wv,
                    const float* __restrict__ bk, const float* __restrict__ bq,
                    const float* __restrict__ bv,
                    const float* __restrict__ rel_att, const float* __restrict__ rel_msg,
                    float* __restrict__ Bbuf, float* __restrict__ biasbuf)
{
    const int din = blockIdx.x;   // 0..255 (input dim)
    const int t   = threadIdx.x;  // 0..255 (output col within segment)
    __shared__ float wk[256], wv[256];
    wk[t] = Wk[din * 256 + t];
    wv[t] = Wv[din * 256 + t];
    __syncthreads();
    const int h = t >> 5, e = t & 31;
    Bbuf[(size_t)din * 1280 + t] = Wq[din * 256 + t];
    #pragma unroll
    for (int r = 0; r < 2; ++r) {
        const float* ra = rel_att + (size_t)((r * 8 + h) * 32) * 32 + e; // stride 32 over d
        const float* rm = rel_msg + (size_t)((r * 8 + h) * 32) * 32 + e;
        float sa = 0.f, sm = 0.f;
        #pragma unroll
        for (int dd = 0; dd < 32; ++dd) {
            sa = fmaf(wk[h * 32 + dd], ra[dd * 32], sa);
            sm = fmaf(wv[h * 32 + dd], rm[dd * 32], sm);
        }
        Bbuf[(size_t)din * 1280 + 256 + r * 512 + t]       = sa;
        Bbuf[(size_t)din * 1280 + 256 + r * 512 + 256 + t] = sm;
    }
    if (din == 0) {
        biasbuf[t] = bq[t];
        #pragma unroll
        for (int r = 0; r < 2; ++r) {
            float sa = 0.f, sm = 0.f;
            #pragma unroll
            for (int dd = 0; dd < 32; ++dd) {
                sa = fmaf(bk[h * 32 + dd], rel_att[(size_t)((r * 8 + h) * 32 + dd) * 32 + e], sa);
                sm = fmaf(bv[h * 32 + dd], rel_msg[(size_t)((r * 8 + h) * 32 + dd) * 32 + e], sm);
            }
            biasbuf[256 + r * 512 + t]       = sa;
            biasbuf[256 + r * 512 + 256 + t] = sm;
        }
    }
}

// ---------------- tiled f32 GEMM: C = alpha*(A@B) + bias ----------------
#define TM 128
#define TN 128
#define TK 16

__global__ __launch_bounds__(256)
void gemm_bias(const float* __restrict__ A, int lda,
               const float* __restrict__ B, int ldb,
               const float* __restrict__ bias,
               float* __restrict__ C, int ldc,
               int M, int K, int Nc, float alpha)
{
    __shared__ float As[TK][TM]; // stored transposed: As[k][m]
    __shared__ float Bs[TK][TN];
    const int tid = threadIdx.x;
    const int bm = blockIdx.x * TM;
    const int bn = blockIdx.y * TN;
    const int tr = tid >> 4;   // 0..15 -> 8 rows each
    const int tc = tid & 15;   // 0..15 -> 2x4 cols each
    float acc[8][8];
    #pragma unroll
    for (int i = 0; i < 8; ++i)
        #pragma unroll
        for (int j = 0; j < 8; ++j) acc[i][j] = 0.f;

    for (int k0 = 0; k0 < K; k0 += TK) {
        #pragma unroll
        for (int i = 0; i < 2; ++i) {
            int s = tid + i * 256;      // 0..511
            int row = s >> 2;           // 0..127
            int c4 = (s & 3) << 2;      // 0,4,8,12
            float4 av = make_float4(0.f, 0.f, 0.f, 0.f);
            if (bm + row < M)
                av = *reinterpret_cast<const float4*>(A + (size_t)(bm + row) * lda + k0 + c4);
            As[c4 + 0][row] = av.x;
            As[c4 + 1][row] = av.y;
            As[c4 + 2][row] = av.z;
            As[c4 + 3][row] = av.w;
        }
        #pragma unroll
        for (int i = 0; i < 2; ++i) {
            int s = tid + i * 256;      // 0..511
            int brow = s >> 5;          // 0..15
            int bc = (s & 31) << 2;     // 0..124
            float4 bv = *reinterpret_cast<const float4*>(B + (size_t)(k0 + brow) * ldb + bn + bc);
            *reinterpret_cast<float4*>(&Bs[brow][bc]) = bv;
        }
        __syncthreads();
        #pragma unroll
        for (int kk = 0; kk < TK; ++kk) {
            float4 a0 = *reinterpret_cast<const float4*>(&As[kk][tr * 8]);
            float4 a1 = *reinterpret_cast<const float4*>(&As[kk][tr * 8 + 4]);
            float4 b0 = *reinterpret_cast<const float4*>(&Bs[kk][tc * 4]);
            float4 b1 = *reinterpret_cast<const float4*>(&Bs[kk][tc * 4 + 64]);
            float a[8] = {a0.x, a0.y, a0.z, a0.w, a1.x, a1.y, a1.z, a1.w};
            float b[8] = {b0.x, b0.y, b0.z, b0.w, b1.x, b1.y, b1.z, b1.w};
            #pragma unroll
            for (int i = 0; i < 8; ++i)
                #pragma unroll
                for (int j = 0; j < 8; ++j)
                    acc[i][j] = fmaf(a[i], b[j], acc[i][j]);
        }
        __syncthreads();
    }
    #pragma unroll
    for (int i = 0; i < 8; ++i) {
        int row = bm + tr * 8 + i;
        if (row < M) {
            int col0 = bn + tc * 4;
            int col1 = bn + tc * 4 + 64;
            float4 o0, o1;
            o0.x = alpha * acc[i][0] + bias[col0 + 0];
            o0.y = alpha * acc[i][1] + bias[col0 + 1];
            o0.z = alpha * acc[i][2] + bias[col0 + 2];
            o0.w = alpha * acc[i][3] + bias[col0 + 3];
            o1.x = alpha * acc[i][4] + bias[col1 + 0];
            o1.y = alpha * acc[i][5] + bias[col1 + 1];
            o1.z = alpha * acc[i][6] + bias[col1 + 2];
            o1.w = alpha * acc[i][7] + bias[col1 + 3];
            *reinterpret_cast<float4*>(C + (size_t)row * ldc + col0) = o0;
            *reinterpret_cast<float4*>(C + (size_t)row * ldc + col1) = o1;
        }
    }
}

// ---------------- CSR build: histogram ----------------
__global__ __launch_bounds__(256)
void hist_kernel(const int* __restrict__ dst, int* __restrict__ deg, int E)
{
    const int stride = gridDim.x * blockDim.x;
    for (int e = blockIdx.x * blockDim.x + threadIdx.x; e < E; e += stride)
        atomicAdd(&deg[dst[e]], 1);
}

// ---------------- CSR build: single-block chunked exclusive scan ----------------
__global__ __launch_bounds__(1024)
void scan_kernel(const int* __restrict__ deg, int* __restrict__ rowptr,
                 int* __restrict__ cursor, int n)
{
    __shared__ int sm[1024];
    __shared__ int carry_s;
    const int tid = threadIdx.x;
    if (tid == 0) carry_s = 0;
    __syncthreads();
    for (int base = 0; base < n; base += 1024) {
        const int i = base + tid;
        const int v = (i < n) ? deg[i] : 0;
        sm[tid] = v;
        __syncthreads();
        for (int off = 1; off < 1024; off <<= 1) {
            int add = (tid >= off) ? sm[tid - off] : 0;
            __syncthreads();
            sm[tid] += add;
            __syncthreads();
        }
        const int excl = sm[tid] - v + carry_s;
        if (i < n) { rowptr[i] = excl; cursor[i] = excl; }
        __syncthreads();
        if (tid == 0) carry_s += sm[1023];
        __syncthreads();
    }
}

// ---------------- CSR build: scatter srcs by dst ----------------
__global__ __launch_bounds__(256)
void scatter_kernel(const int* __restrict__ src, const int* __restrict__ dst,
                    int* __restrict__ cursor, int* __restrict__ srcs, int E)
{
    const int stride = gridDim.x * blockDim.x;
    for (int e = blockIdx.x * blockDim.x + threadIdx.x; e < E; e += stride) {
        int pos = atomicAdd(&cursor[dst[e]], 1);
        srcs[pos] = src[e];
    }
}

// ---------------- fused online-softmax aggregation: one wave per node ----------------
// lane l (0..63): head h = l>>3, owns QKV-row float4 slot l (dims [4l,4l+4)).
// After scatter, cursor[n] == rowptr[n] + deg[n] (end pointer).
__global__ __launch_bounds__(256)
void node_agg_kernel(const float* __restrict__ QKV,
                     const int* __restrict__ rowptr, const int* __restrict__ endptr,
                     const int* __restrict__ srcs,
                     const float* __restrict__ pri8,   // rel_pri + r*8
                     float* __restrict__ AGG, int accumulate)
{
    const int node = (blockIdx.x * blockDim.x + threadIdx.x) >> 6;
    if (node >= NN) return;
    const int l = threadIdx.x & 63;
    const int h = l >> 3;
    const float4 q4 = reinterpret_cast<const float4*>(QKV + (size_t)node * 768)[l];
    const float prh = pri8[h] * INV_SQRT_DK;
    const int s0 = rowptr[node];
    const int s1 = endptr[node];
    float m = -3.0e38f, den = 0.f;
    float4 acc = make_float4(0.f, 0.f, 0.f, 0.f);
    for (int i = s0; i < s1; ++i) {
        const int s = srcs[i];
        const float4* row = reinterpret_cast<const float4*>(QKV + (size_t)s * 768);
        const float4 k4 = row[64 + l];    // kr (floats 256..511)
        float p = q4.x * k4.x + q4.y * k4.y + q4.z * k4.z + q4.w * k4.w;
        p += __shfl_xor(p, 1, 64);
        p += __shfl_xor(p, 2, 64);
        p += __shfl_xor(p, 4, 64);        // full 32-dim head dot in all 8 lanes of group
        const float sc = p * prh;
        const float mnew = fmaxf(m, sc);
        const float scale = __expf(m - mnew);   // first iter: exp(-huge) = 0
        const float ex = __expf(sc - mnew);
        const float4 v4 = row[128 + l];   // vr (floats 512..767)
        den = den * scale + ex;
        acc.x = acc.x * scale + v4.x * ex;
        acc.y = acc.y * scale + v4.y * ex;
        acc.z = acc.z * scale + v4.z * ex;
        acc.w = acc.w * scale + v4.w * ex;
        m = mnew;
    }
    const float inv = (s1 > s0) ? 1.0f / den : 0.f;
    float4 o = make_float4(acc.x * inv, acc.y * inv, acc.z * inv, acc.w * inv);
    float4* outp = reinterpret_cast<float4*>(AGG + (size_t)node * 256);
    if (accumulate) {
        const float4 prev = outp[l];
        o.x += prev.x; o.y += prev.y; o.z += prev.z; o.w += prev.w;
    }
    outp[l] = o;
}

// ---------------- residual + LayerNorm ----------------
__global__ __launch_bounds__(256)
void ln_kernel(const float* __restrict__ tmp, const float* __restrict__ hres,
               const float* __restrict__ g, const float* __restrict__ b,
               float* __restrict__ out, int M)
{
    const int gtid = blockIdx.x * blockDim.x + threadIdx.x;
    const int wid = gtid >> 6;
    const int nw = (gridDim.x * blockDim.x) >> 6;
    const int lane = threadIdx.x & 63;
    const float4 gv = reinterpret_cast<const float4*>(g)[lane];
    const float4 bv = reinterpret_cast<const float4*>(b)[lane];
    for (int row = wid; row < M; row += nw) {
        const float4 tv = reinterpret_cast<const float4*>(tmp + (size_t)row * 256)[lane];
        const float4 hv = reinterpret_cast<const float4*>(hres + (size_t)row * 256)[lane];
        float y0 = tv.x + hv.x, y1 = tv.y + hv.y, y2 = tv.z + hv.z, y3 = tv.w + hv.w;
        float ssum = y0 + y1 + y2 + y3;
        #pragma unroll
        for (int off = 32; off; off >>= 1) ssum += __shfl_xor(ssum, off, 64);
        const float mean = ssum * (1.f / 256.f);
        const float d0 = y0 - mean, d1 = y1 - mean, d2 = y2 - mean, d3 = y3 - mean;
        float sq = d0 * d0 + d1 * d1 + d2 * d2 + d3 * d3;
        #pragma unroll
        for (int off = 32; off; off >>= 1) sq += __shfl_xor(sq, off, 64);
        const float inv = rsqrtf(sq * (1.f / 256.f) + 1e-5f);
        float4 o;
        o.x = d0 * inv * gv.x + bv.x;
        o.y = d1 * inv * gv.y + bv.y;
        o.z = d2 * inv * gv.z + bv.z;
        o.w = d3 * inv * gv.w + bv.w;
        reinterpret_cast<float4*>(out + (size_t)row * 256)[lane] = o;
    }
}

extern "C" void kernel_launch(void* const* d_in, const int* in_sizes, int n_in,
                              void* d_out, int out_size, void* d_ws, size_t ws_size,
                              hipStream_t stream)
{
    const float* h    = (const float*)d_in[0];
    const int* src0   = (const int*)d_in[1];
    const int* dst0   = (const int*)d_in[2];
    const int* src1   = (const int*)d_in[3];
    const int* dst1   = (const int*)d_in[4];
    const float* Wk   = (const float*)d_in[5];
    const float* bk   = (const float*)d_in[6];
    const float* Wq   = (const float*)d_in[7];
    const float* bq   = (const float*)d_in[8];
    const float* Wv   = (const float*)d_in[9];
    const float* bv   = (const float*)d_in[10];
    const float* Wa   = (const float*)d_in[11];
    const float* ba   = (const float*)d_in[12];
    const float* lng  = (const float*)d_in[13];
    const float* lnb  = (const float*)d_in[14];
    const float* rel_pri = (const float*)d_in[15];
    const float* rel_att = (const float*)d_in[16];
    const float* rel_msg = (const float*)d_in[17];

    float* ws    = (float*)d_ws;
    float* QKV   = ws + OFF_QKV;
    float* BBUF  = ws + OFF_B;
    float* BIAS  = ws + OFF_BIAS;
    int* DEG     = (int*)(ws + OFF_DEG);
    int* ROWPTR  = (int*)(ws + OFF_ROWPTR);
    int* CURSOR  = (int*)(ws + OFF_CURSOR);
    int* SRCS    = (int*)(ws + OFF_SRCS);
    float* AGG   = (float*)d_out;   // [N][256] scratch until final LN

    // fused weights
    build_B_kernel<<<256, 256, 0, stream>>>(Wk, Wq, Wv, bk, bq, bv,
                                            rel_att, rel_msg, BBUF, BIAS);

    // GEMM1: [N,256] x [256,768] -> q | kr0 | vr0
    {
        dim3 grid((NN + TM - 1) / TM, 768 / TN);
        gemm_bias<<<grid, 256, 0, stream>>>(h, 256, BBUF, 1280, BIAS,
                                            QKV, 768, NN, 256, 768, 1.0f);
    }
    // relation 0: CSR build + fused aggregation (writes AGG, no zero needed)
    zero_kernel<<<128, 256, 0, stream>>>((float4*)DEG, (long)NN / 4);
    hist_kernel<<<1024, 256, 0, stream>>>(dst0, DEG, EE);
    scan_kernel<<<1, 1024, 0, stream>>>(DEG, ROWPTR, CURSOR, NN);
    scatter_kernel<<<1024, 256, 0, stream>>>(src0, dst0, CURSOR, SRCS, EE);
    node_agg_kernel<<<NN * 64 / 256, 256, 0, stream>>>(QKV, ROWPTR, CURSOR, SRCS,
                                                       rel_pri + 0, AGG, 0);

    // GEMM2: [N,256] x [256,512] -> kr1 | vr1 (overwrites kr0|vr0, q kept)
    {
        dim3 grid((NN + TM - 1) / TM, 512 / TN);
        gemm_bias<<<grid, 256, 0, stream>>>(h, 256, BBUF + 768, 1280, BIAS + 768,
                                            QKV + 256, 768, NN, 256, 512, 1.0f);
    }
    // relation 1
    zero_kernel<<<128, 256, 0, stream>>>((float4*)DEG, (long)NN / 4);
    hist_kernel<<<1024, 256, 0, stream>>>(dst1, DEG, EE);
    scan_kernel<<<1, 1024, 0, stream>>>(DEG, ROWPTR, CURSOR, NN);
    scatter_kernel<<<1024, 256, 0, stream>>>(src1, dst1, CURSOR, SRCS, EE);
    node_agg_kernel<<<NN * 64 / 256, 256, 0, stream>>>(QKV, ROWPTR, CURSOR, SRCS,
                                                       rel_pri + 8, AGG, 1);

    // output projection: tmp = 0.5*(agg @ Wa) + ba   (tmp aliases dead QKV region)
    float* TMP = ws + OFF_QKV;
    {
        dim3 grid((NN + TM - 1) / TM, 256 / TN);
        gemm_bias<<<grid, 256, 0, stream>>>(AGG, 256, Wa, 256, ba,
                                            TMP, 256, NN, 256, 256, 0.5f);
    }
    // residual + layernorm (reads TMP, overwrites d_out)
    ln_kernel<<<2048, 256, 0, stream>>>(TMP, h, lng, lnb, (float*)d_out, NN);
}

// Round 5
// 1888.414 us; speedup vs baseline: 1.2629x; 1.0063x over previous
//
#include <hip/hip_runtime.h>
#include <cstdint>
#include <cstddef>

// HGT layer: N=100000, E=400000/rel, D=256, H=8, DK=32, R=2.
// Round 4: GEMMs -> split-bf16 MFMA (3-term: AhiBhi + AloBhi + AhiBlo as one
// K=768 bf16 GEMM). Edge phase (CSR + fused online-softmax) unchanged.
// Fallback to f32 GEMM path if ws_size < 416 MB (round-2 crash was possibly
// ws overflow at 437 MB; 311 MB known good).

#define NN 100000
#define EE 400000

static constexpr float INV_SQRT_DK = 0.17677669529663687f; // 1/sqrt(32)

// ---------------- workspace layout (float offsets) ----------------
static constexpr size_t OFF_QKV    = 0;                                  // [N][768] f32
static constexpr size_t OFF_BBUF   = OFF_QKV    + (size_t)NN * 768;      // [256][1280] f32
static constexpr size_t OFF_BIAS   = OFF_BBUF   + (size_t)256 * 1280;    // [1280]
static constexpr size_t OFF_DEG    = OFF_BIAS   + 1280;                  // [N] int
static constexpr size_t OFF_ROWPTR = OFF_DEG    + NN;                    // [N] int
static constexpr size_t OFF_CURSOR = OFF_ROWPTR + NN;                    // [N] int
static constexpr size_t OFF_SRCS   = OFF_CURSOR + NN;                    // [E] int
static constexpr size_t OFF_BASE_END = OFF_SRCS + EE;                    // 311.3 MB
// MFMA-path extras:
static constexpr size_t OFF_ASPLIT = OFF_BASE_END;                       // [N][512] bf16 (as 2B units)
static constexpr size_t OFF_BT     = OFF_ASPLIT + (size_t)NN * 256;      // [1536][512] bf16
static constexpr size_t OFF_END    = OFF_BT + (size_t)1536 * 512 / 2;    // floats

using bf16x8 = __attribute__((ext_vector_type(8))) __bf16;
using f32x4v = __attribute__((ext_vector_type(4))) float;
using u32x4  = __attribute__((ext_vector_type(4))) unsigned int;

static __device__ inline unsigned short bf_bits(__bf16 b) {
    union { __bf16 b; unsigned short u; } x; x.b = b; return x.u;
}

// ---------------- zero fill ----------------
__global__ __launch_bounds__(256)
void zero_kernel(float4* __restrict__ p, long n4)
{
    const long stride = (long)gridDim.x * blockDim.x;
    for (long i = (long)blockIdx.x * blockDim.x + threadIdx.x; i < n4; i += stride)
        p[i] = make_float4(0.f, 0.f, 0.f, 0.f);
}

// ---------------- fused weight build (f32) ----------------
__global__ __launch_bounds__(256)
void build_B_kernel(const float* __restrict__ Wk, const float* __restrict__ Wq,
                    const float* __restrict__ Wv,
                    const float* __restrict__ bk, const float* __restrict__ bq,
                    const float* __restrict__ bv,
                    const float* __restrict__ rel_att, const float* __restrict__ rel_msg,
                    float* __restrict__ Bbuf, float* __restrict__ biasbuf)
{
    const int din = blockIdx.x;   // 0..255 (input dim)
    const int t   = threadIdx.x;  // 0..255 (output col within segment)
    __shared__ float wk[256], wv[256];
    wk[t] = Wk[din * 256 + t];
    wv[t] = Wv[din * 256 + t];
    __syncthreads();
    const int h = t >> 5, e = t & 31;
    Bbuf[(size_t)din * 1280 + t] = Wq[din * 256 + t];
    #pragma unroll
    for (int r = 0; r < 2; ++r) {
        const float* ra = rel_att + (size_t)((r * 8 + h) * 32) * 32 + e;
        const float* rm = rel_msg + (size_t)((r * 8 + h) * 32) * 32 + e;
        float sa = 0.f, sm = 0.f;
        #pragma unroll
        for (int dd = 0; dd < 32; ++dd) {
            sa = fmaf(wk[h * 32 + dd], ra[dd * 32], sa);
            sm = fmaf(wv[h * 32 + dd], rm[dd * 32], sm);
        }
        Bbuf[(size_t)din * 1280 + 256 + r * 512 + t]       = sa;
        Bbuf[(size_t)din * 1280 + 256 + r * 512 + 256 + t] = sm;
    }
    if (din == 0) {
        biasbuf[t] = bq[t];
        #pragma unroll
        for (int r = 0; r < 2; ++r) {
            float sa = 0.f, sm = 0.f;
            #pragma unroll
            for (int dd = 0; dd < 32; ++dd) {
                sa = fmaf(bk[h * 32 + dd], rel_att[(size_t)((r * 8 + h) * 32 + dd) * 32 + e], sa);
                sm = fmaf(bv[h * 32 + dd], rel_msg[(size_t)((r * 8 + h) * 32 + dd) * 32 + e], sm);
            }
            biasbuf[256 + r * 512 + t]       = sa;
            biasbuf[256 + r * 512 + 256 + t] = sm;
        }
    }
}

// ---------------- split conversions ----------------
// src [M][256] f32 -> dst [M][512] bf16 bits (cols 0..255 hi, 256..511 lo)
__global__ __launch_bounds__(256)
void conv_split_kernel(const float* __restrict__ src, unsigned short* __restrict__ dst, long m)
{
    const long total = m * 64;  // float4 units
    const long stride = (long)gridDim.x * blockDim.x;
    for (long i = (long)blockIdx.x * blockDim.x + threadIdx.x; i < total; i += stride) {
        const long row = i >> 6;
        const int c4 = (int)(i & 63);
        const float4 v = reinterpret_cast<const float4*>(src)[i];
        __bf16 h0 = (__bf16)v.x, h1 = (__bf16)v.y, h2 = (__bf16)v.z, h3 = (__bf16)v.w;
        __bf16 l0 = (__bf16)(v.x - (float)h0);
        __bf16 l1 = (__bf16)(v.y - (float)h1);
        __bf16 l2 = (__bf16)(v.z - (float)h2);
        __bf16 l3 = (__bf16)(v.w - (float)h3);
        ushort4 hv = make_ushort4(bf_bits(h0), bf_bits(h1), bf_bits(h2), bf_bits(h3));
        ushort4 lv = make_ushort4(bf_bits(l0), bf_bits(l1), bf_bits(l2), bf_bits(l3));
        *reinterpret_cast<ushort4*>(dst + row * 512 + c4 * 4)       = hv;
        *reinterpret_cast<ushort4*>(dst + row * 512 + 256 + c4 * 4) = lv;
    }
}

// BBUF [256][1280] + Wa [256][256] -> BT [1536][512] bf16 bits (n-major, k inner; hi|lo)
__global__ __launch_bounds__(256)
void conv_B_kernel(const float* __restrict__ Bbuf, const float* __restrict__ Wa,
                   unsigned short* __restrict__ BT)
{
    const int n = blockIdx.x;    // 0..1535
    const int k = threadIdx.x;   // 0..255
    const float v = (n < 1280) ? Bbuf[(size_t)k * 1280 + n]
                               : Wa[(size_t)k * 256 + (n - 1280)];
    __bf16 hi = (__bf16)v;
    __bf16 lo = (__bf16)(v - (float)hi);
    BT[(size_t)n * 512 + k]       = bf_bits(hi);
    BT[(size_t)n * 512 + 256 + k] = bf_bits(lo);
}

// ---------------- split-bf16 MFMA GEMM ----------------
// C[M][ldc] = alpha * (A_f32 @ B_f32) + bias, via 3-term split over K'=768.
// Asp: [M][512] bf16 (hi|lo), BTs: [NB][512] bf16 n-major (hi|lo), pre-offset.
// 128x128 tile, BK=64, 4 waves (2x2), per-wave 64x64 via 4x4 16x16x32 frags.
__global__ __launch_bounds__(256)
void gemm_mfma(const unsigned short* __restrict__ Asp,
               const unsigned short* __restrict__ BTs,
               const float* __restrict__ bias,
               float* __restrict__ C, int ldc,
               int M, float alpha)
{
    __shared__ __align__(16) unsigned short AsB[128 * 64];
    __shared__ __align__(16) unsigned short BsB[128 * 64];
    const int tid = threadIdx.x;
    const int bm = blockIdx.x * 128;
    const int bn = blockIdx.y * 128;
    const int wid = tid >> 6;
    const int l   = tid & 63;
    const int wm  = (wid >> 1) * 64;
    const int wn  = (wid & 1) * 64;
    const int l15 = l & 15;
    const int lk  = (l >> 4) * 8;   // k sub-offset (contiguous-8 per 16-lane group)

    f32x4v acc[4][4];
    #pragma unroll
    for (int i = 0; i < 4; ++i)
        #pragma unroll
        for (int j = 0; j < 4; ++j)
            acc[i][j] = (f32x4v){0.f, 0.f, 0.f, 0.f};

    u32x4 ra[4], rb[4];

    auto g_load = [&](int step) {
        const int ak0 = ((step & 3) << 6) + (((step >> 2) == 1) ? 256 : 0);
        const int bk0 = ((step & 3) << 6) + (((step >> 2) == 2) ? 256 : 0);
        #pragma unroll
        for (int it = 0; it < 4; ++it) {
            const int idx = it * 256 + tid;
            const int row = idx >> 3, ch = idx & 7;
            const int grow = bm + row;
            if (grow < M)
                ra[it] = *reinterpret_cast<const u32x4*>(Asp + (size_t)grow * 512 + ak0 + ch * 8);
            else
                ra[it] = (u32x4){0u, 0u, 0u, 0u};
            rb[it] = *reinterpret_cast<const u32x4*>(BTs + (size_t)(bn + row) * 512 + bk0 + ch * 8);
        }
    };

    g_load(0);

    for (int step = 0; step < 12; ++step) {
        __syncthreads();   // previous compute done reading LDS
        #pragma unroll
        for (int it = 0; it < 4; ++it) {
            const int idx = it * 256 + tid;
            const int row = idx >> 3, ch = idx & 7;
            const int byteoff = (row * 128 + ch * 16) ^ ((row & 7) << 4);
            *reinterpret_cast<u32x4*>(reinterpret_cast<char*>(AsB) + byteoff) = ra[it];
            *reinterpret_cast<u32x4*>(reinterpret_cast<char*>(BsB) + byteoff) = rb[it];
        }
        __syncthreads();
        if (step < 11) g_load(step + 1);   // overlap next-step global loads with MFMA
        #pragma unroll
        for (int kk = 0; kk < 2; ++kk) {
            bf16x8 af[4], bfr[4];
            #pragma unroll
            for (int i = 0; i < 4; ++i) {
                const int arow = wm + i * 16 + l15;
                const int abyte = (arow * 128 + (kk * 32 + lk) * 2) ^ ((arow & 7) << 4);
                af[i] = *reinterpret_cast<const bf16x8*>(reinterpret_cast<const char*>(AsB) + abyte);
                const int brow = wn + i * 16 + l15;
                const int bbyte = (brow * 128 + (kk * 32 + lk) * 2) ^ ((brow & 7) << 4);
                bfr[i] = *reinterpret_cast<const bf16x8*>(reinterpret_cast<const char*>(BsB) + bbyte);
            }
            #pragma unroll
            for (int i = 0; i < 4; ++i)
                #pragma unroll
                for (int j = 0; j < 4; ++j)
                    acc[i][j] = __builtin_amdgcn_mfma_f32_16x16x32_bf16(af[i], bfr[j], acc[i][j], 0, 0, 0);
        }
    }

    // epilogue: C/D layout col=lane&15, row=(lane>>4)*4+r  (m89-verified)
    #pragma unroll
    for (int i = 0; i < 4; ++i) {
        const int rbase = bm + wm + i * 16 + (l >> 4) * 4;
        #pragma unroll
        for (int j = 0; j < 4; ++j) {
            const int col = bn + wn + j * 16 + l15;
            const float bcol = bias[col];
            #pragma unroll
            for (int r = 0; r < 4; ++r) {
                const int row = rbase + r;
                if (row < M)
                    C[(size_t)row * ldc + col] = alpha * acc[i][j][r] + bcol;
            }
        }
    }
}

// ---------------- f32 GEMM (fallback path) ----------------
#define TM 128
#define TN 128
#define TK 16

__global__ __launch_bounds__(256)
void gemm_bias(const float* __restrict__ A, int lda,
               const float* __restrict__ B, int ldb,
               const float* __restrict__ bias,
               float* __restrict__ C, int ldc,
               int M, int K, int Nc, float alpha)
{
    __shared__ float As[TK][TM];
    __shared__ float Bs[TK][TN];
    const int tid = threadIdx.x;
    const int bm = blockIdx.x * TM;
    const int bn = blockIdx.y * TN;
    const int tr = tid >> 4;
    const int tc = tid & 15;
    float acc[8][8];
    #pragma unroll
    for (int i = 0; i < 8; ++i)
        #pragma unroll
        for (int j = 0; j < 8; ++j) acc[i][j] = 0.f;

    for (int k0 = 0; k0 < K; k0 += TK) {
        #pragma unroll
        for (int i = 0; i < 2; ++i) {
            int s = tid + i * 256;
            int row = s >> 2;
            int c4 = (s & 3) << 2;
            float4 av = make_float4(0.f, 0.f, 0.f, 0.f);
            if (bm + row < M)
                av = *reinterpret_cast<const float4*>(A + (size_t)(bm + row) * lda + k0 + c4);
            As[c4 + 0][row] = av.x;
            As[c4 + 1][row] = av.y;
            As[c4 + 2][row] = av.z;
            As[c4 + 3][row] = av.w;
        }
        #pragma unroll
        for (int i = 0; i < 2; ++i) {
            int s = tid + i * 256;
            int brow = s >> 5;
            int bc = (s & 31) << 2;
            float4 bv = *reinterpret_cast<const float4*>(B + (size_t)(k0 + brow) * ldb + bn + bc);
            *reinterpret_cast<float4*>(&Bs[brow][bc]) = bv;
        }
        __syncthreads();
        #pragma unroll
        for (int kk = 0; kk < TK; ++kk) {
            float4 a0 = *reinterpret_cast<const float4*>(&As[kk][tr * 8]);
            float4 a1 = *reinterpret_cast<const float4*>(&As[kk][tr * 8 + 4]);
            float4 b0 = *reinterpret_cast<const float4*>(&Bs[kk][tc * 4]);
            float4 b1 = *reinterpret_cast<const float4*>(&Bs[kk][tc * 4 + 64]);
            float a[8] = {a0.x, a0.y, a0.z, a0.w, a1.x, a1.y, a1.z, a1.w};
            float b[8] = {b0.x, b0.y, b0.z, b0.w, b1.x, b1.y, b1.z, b1.w};
            #pragma unroll
            for (int i = 0; i < 8; ++i)
                #pragma unroll
                for (int j = 0; j < 8; ++j)
                    acc[i][j] = fmaf(a[i], b[j], acc[i][j]);
        }
        __syncthreads();
    }
    #pragma unroll
    for (int i = 0; i < 8; ++i) {
        int row = bm + tr * 8 + i;
        if (row < M) {
            int col0 = bn + tc * 4;
            int col1 = bn + tc * 4 + 64;
            float4 o0, o1;
            o0.x = alpha * acc[i][0] + bias[col0 + 0];
            o0.y = alpha * acc[i][1] + bias[col0 + 1];
            o0.z = alpha * acc[i][2] + bias[col0 + 2];
            o0.w = alpha * acc[i][3] + bias[col0 + 3];
            o1.x = alpha * acc[i][4] + bias[col1 + 0];
            o1.y = alpha * acc[i][5] + bias[col1 + 1];
            o1.z = alpha * acc[i][6] + bias[col1 + 2];
            o1.w = alpha * acc[i][7] + bias[col1 + 3];
            *reinterpret_cast<float4*>(C + (size_t)row * ldc + col0) = o0;
            *reinterpret_cast<float4*>(C + (size_t)row * ldc + col1) = o1;
        }
    }
}

// ---------------- CSR build ----------------
__global__ __launch_bounds__(256)
void hist_kernel(const int* __restrict__ dst, int* __restrict__ deg, int E)
{
    const int stride = gridDim.x * blockDim.x;
    for (int e = blockIdx.x * blockDim.x + threadIdx.x; e < E; e += stride)
        atomicAdd(&deg[dst[e]], 1);
}

__global__ __launch_bounds__(1024)
void scan_kernel(const int* __restrict__ deg, int* __restrict__ rowptr,
                 int* __restrict__ cursor, int n)
{
    __shared__ int sm[1024];
    __shared__ int carry_s;
    const int tid = threadIdx.x;
    if (tid == 0) carry_s = 0;
    __syncthreads();
    for (int base = 0; base < n; base += 1024) {
        const int i = base + tid;
        const int v = (i < n) ? deg[i] : 0;
        sm[tid] = v;
        __syncthreads();
        for (int off = 1; off < 1024; off <<= 1) {
            int add = (tid >= off) ? sm[tid - off] : 0;
            __syncthreads();
            sm[tid] += add;
            __syncthreads();
        }
        const int excl = sm[tid] - v + carry_s;
        if (i < n) { rowptr[i] = excl; cursor[i] = excl; }
        __syncthreads();
        if (tid == 0) carry_s += sm[1023];
        __syncthreads();
    }
}

__global__ __launch_bounds__(256)
void scatter_kernel(const int* __restrict__ src, const int* __restrict__ dst,
                    int* __restrict__ cursor, int* __restrict__ srcs, int E)
{
    const int stride = gridDim.x * blockDim.x;
    for (int e = blockIdx.x * blockDim.x + threadIdx.x; e < E; e += stride) {
        int pos = atomicAdd(&cursor[dst[e]], 1);
        srcs[pos] = src[e];
    }
}

// ---------------- fused online-softmax aggregation: one wave per node ----------------
__global__ __launch_bounds__(256)
void node_agg_kernel(const float* __restrict__ QKV,
                     const int* __restrict__ rowptr, const int* __restrict__ endptr,
                     const int* __restrict__ srcs,
                     const float* __restrict__ pri8,
                     float* __restrict__ AGG, int accumulate)
{
    const int node = (blockIdx.x * blockDim.x + threadIdx.x) >> 6;
    if (node >= NN) return;
    const int l = threadIdx.x & 63;
    const int h = l >> 3;
    const float4 q4 = reinterpret_cast<const float4*>(QKV + (size_t)node * 768)[l];
    const float prh = pri8[h] * INV_SQRT_DK;
    const int s0 = rowptr[node];
    const int s1 = endptr[node];
    float m = -3.0e38f, den = 0.f;
    float4 acc = make_float4(0.f, 0.f, 0.f, 0.f);
    for (int i = s0; i < s1; ++i) {
        const int s = srcs[i];
        const float4* row = reinterpret_cast<const float4*>(QKV + (size_t)s * 768);
        const float4 k4 = row[64 + l];
        float p = q4.x * k4.x + q4.y * k4.y + q4.z * k4.z + q4.w * k4.w;
        p += __shfl_xor(p, 1, 64);
        p += __shfl_xor(p, 2, 64);
        p += __shfl_xor(p, 4, 64);
        const float sc = p * prh;
        const float mnew = fmaxf(m, sc);
        const float scale = __expf(m - mnew);
        const float ex = __expf(sc - mnew);
        const float4 v4 = row[128 + l];
        den = den * scale + ex;
        acc.x = acc.x * scale + v4.x * ex;
        acc.y = acc.y * scale + v4.y * ex;
        acc.z = acc.z * scale + v4.z * ex;
        acc.w = acc.w * scale + v4.w * ex;
        m = mnew;
    }
    const float inv = (s1 > s0) ? 1.0f / den : 0.f;
    float4 o = make_float4(acc.x * inv, acc.y * inv, acc.z * inv, acc.w * inv);
    float4* outp = reinterpret_cast<float4*>(AGG + (size_t)node * 256);
    if (accumulate) {
        const float4 prev = outp[l];
        o.x += prev.x; o.y += prev.y; o.z += prev.z; o.w += prev.w;
    }
    outp[l] = o;
}

// ---------------- residual + LayerNorm ----------------
__global__ __launch_bounds__(256)
void ln_kernel(const float* __restrict__ tmp, const float* __restrict__ hres,
               const float* __restrict__ g, const float* __restrict__ b,
               float* __restrict__ out, int M)
{
    const int gtid = blockIdx.x * blockDim.x + threadIdx.x;
    const int wid = gtid >> 6;
    const int nw = (gridDim.x * blockDim.x) >> 6;
    const int lane = threadIdx.x & 63;
    const float4 gv = reinterpret_cast<const float4*>(g)[lane];
    const float4 bv = reinterpret_cast<const float4*>(b)[lane];
    for (int row = wid; row < M; row += nw) {
        const float4 tv = reinterpret_cast<const float4*>(tmp + (size_t)row * 256)[lane];
        const float4 hv = reinterpret_cast<const float4*>(hres + (size_t)row * 256)[lane];
        float y0 = tv.x + hv.x, y1 = tv.y + hv.y, y2 = tv.z + hv.z, y3 = tv.w + hv.w;
        float ssum = y0 + y1 + y2 + y3;
        #pragma unroll
        for (int off = 32; off; off >>= 1) ssum += __shfl_xor(ssum, off, 64);
        const float mean = ssum * (1.f / 256.f);
        const float d0 = y0 - mean, d1 = y1 - mean, d2 = y2 - mean, d3 = y3 - mean;
        float sq = d0 * d0 + d1 * d1 + d2 * d2 + d3 * d3;
        #pragma unroll
        for (int off = 32; off; off >>= 1) sq += __shfl_xor(sq, off, 64);
        const float inv = rsqrtf(sq * (1.f / 256.f) + 1e-5f);
        float4 o;
        o.x = d0 * inv * gv.x + bv.x;
        o.y = d1 * inv * gv.y + bv.y;
        o.z = d2 * inv * gv.z + bv.z;
        o.w = d3 * inv * gv.w + bv.w;
        reinterpret_cast<float4*>(out + (size_t)row * 256)[lane] = o;
    }
}

extern "C" void kernel_launch(void* const* d_in, const int* in_sizes, int n_in,
                              void* d_out, int out_size, void* d_ws, size_t ws_size,
                              hipStream_t stream)
{
    const float* h    = (const float*)d_in[0];
    const int* src0   = (const int*)d_in[1];
    const int* dst0   = (const int*)d_in[2];
    const int* src1   = (const int*)d_in[3];
    const int* dst1   = (const int*)d_in[4];
    const float* Wk   = (const float*)d_in[5];
    const float* bk   = (const float*)d_in[6];
    const float* Wq   = (const float*)d_in[7];
    const float* bq   = (const float*)d_in[8];
    const float* Wv   = (const float*)d_in[9];
    const float* bv   = (const float*)d_in[10];
    const float* Wa   = (const float*)d_in[11];
    const float* ba   = (const float*)d_in[12];
    const float* lng  = (const float*)d_in[13];
    const float* lnb  = (const float*)d_in[14];
    const float* rel_pri = (const float*)d_in[15];
    const float* rel_att = (const float*)d_in[16];
    const float* rel_msg = (const float*)d_in[17];

    float* ws    = (float*)d_ws;
    float* QKV   = ws + OFF_QKV;
    float* BBUF  = ws + OFF_BBUF;
    float* BIAS  = ws + OFF_BIAS;
    int* DEG     = (int*)(ws + OFF_DEG);
    int* ROWPTR  = (int*)(ws + OFF_ROWPTR);
    int* CURSOR  = (int*)(ws + OFF_CURSOR);
    int* SRCS    = (int*)(ws + OFF_SRCS);
    unsigned short* ASPLIT = (unsigned short*)(ws + OFF_ASPLIT);
    unsigned short* BT     = (unsigned short*)(ws + OFF_BT);
    float* AGG   = (float*)d_out;   // scratch until final LN
    float* TMP   = ws + OFF_QKV;    // GEMM3 output aliases dead QKV

    const bool mfma_path = (ws_size >= OFF_END * sizeof(float));

    // fused weights (both paths)
    build_B_kernel<<<256, 256, 0, stream>>>(Wk, Wq, Wv, bk, bq, bv,
                                            rel_att, rel_msg, BBUF, BIAS);

    if (mfma_path) {
        conv_B_kernel<<<1536, 256, 0, stream>>>(BBUF, Wa, BT);
        conv_split_kernel<<<2048, 256, 0, stream>>>(h, ASPLIT, NN);
        // GEMM1: q | kr0 | vr0
        {
            dim3 grid((NN + 127) / 128, 768 / 128);
            gemm_mfma<<<grid, 256, 0, stream>>>(ASPLIT, BT, BIAS, QKV, 768, NN, 1.0f);
        }
    } else {
        dim3 grid((NN + TM - 1) / TM, 768 / TN);
        gemm_bias<<<grid, 256, 0, stream>>>(h, 256, BBUF, 1280, BIAS, QKV, 768, NN, 256, 768, 1.0f);
    }

    // relation 0
    zero_kernel<<<128, 256, 0, stream>>>((float4*)DEG, (long)NN / 4);
    hist_kernel<<<1024, 256, 0, stream>>>(dst0, DEG, EE);
    scan_kernel<<<1, 1024, 0, stream>>>(DEG, ROWPTR, CURSOR, NN);
    scatter_kernel<<<1024, 256, 0, stream>>>(src0, dst0, CURSOR, SRCS, EE);
    node_agg_kernel<<<NN * 64 / 256, 256, 0, stream>>>(QKV, ROWPTR, CURSOR, SRCS,
                                                       rel_pri + 0, AGG, 0);

    // GEMM2: kr1 | vr1 (q kept)
    if (mfma_path) {
        dim3 grid((NN + 127) / 128, 512 / 128);
        gemm_mfma<<<grid, 256, 0, stream>>>(ASPLIT, BT + (size_t)768 * 512, BIAS + 768,
                                            QKV + 256, 768, NN, 1.0f);
    } else {
        dim3 grid((NN + TM - 1) / TM, 512 / TN);
        gemm_bias<<<grid, 256, 0, stream>>>(h, 256, BBUF + 768, 1280, BIAS + 768,
                                            QKV + 256, 768, NN, 256, 512, 1.0f);
    }

    // relation 1
    zero_kernel<<<128, 256, 0, stream>>>((float4*)DEG, (long)NN / 4);
    hist_kernel<<<1024, 256, 0, stream>>>(dst1, DEG, EE);
    scan_kernel<<<1, 1024, 0, stream>>>(DEG, ROWPTR, CURSOR, NN);
    scatter_kernel<<<1024, 256, 0, stream>>>(src1, dst1, CURSOR, SRCS, EE);
    node_agg_kernel<<<NN * 64 / 256, 256, 0, stream>>>(QKV, ROWPTR, CURSOR, SRCS,
                                                       rel_pri + 8, AGG, 1);

    // GEMM3: tmp = 0.5*(agg @ Wa) + ba
    if (mfma_path) {
        conv_split_kernel<<<2048, 256, 0, stream>>>(AGG, ASPLIT, NN);
        dim3 grid((NN + 127) / 128, 256 / 128);
        gemm_mfma<<<grid, 256, 0, stream>>>(ASPLIT, BT + (size_t)1280 * 512, ba,
                                            TMP, 256, NN, 0.5f);
    } else {
        dim3 grid((NN + TM - 1) / TM, 256 / TN);
        gemm_bias<<<grid, 256, 0, stream>>>(AGG, 256, Wa, 256, ba, TMP, 256, NN, 256, 256, 0.5f);
    }

    // residual + layernorm
    ln_kernel<<<2048, 256, 0, stream>>>(TMP, h, lng, lnb, (float*)d_out, NN);
}

// Round 6
// 1434.456 us; speedup vs baseline: 1.6626x; 1.3165x over previous
//
#include <hip/hip_runtime.h>
#include <cstdint>
#include <cstddef>

// HGT layer: N=100000, E=400000/rel, D=256, H=8, DK=32, R=2.
// Round 6: split-bf16 MFMA GEMM with IN-KERNEL A conversion (no ASPLIT buffer)
// -> total ws usage 311.18 MB, strictly under the proven-good 311.32 MB
// (round-5 evidence: ws_size in [311.3, 415.3) MB -> old MFMA gate fell back).
//   - BT [1536][512] bf16 (hi|lo, n-major) = fused [Wq|Wk@att0|Wv@msg0|Wk@att1|Wv@msg1|Wa]
//   - gemm_mfma: 128x128 tile, 4 waves, 8 f32-K chunks x 3 split terms
//     (AhiBhi + AloBhi + AhiBlo), XOR-swizzled LDS, reg-staged prefetch.
//   - Edge phase: CSR (hist->in-place scan->scatter) + fused online-softmax
//     node aggregation (1 wave/node, single non-atomic 1KB write), unchanged.

#define NN 100000
#define EE 400000

static constexpr float INV_SQRT_DK = 0.17677669529663687f; // 1/sqrt(32)

// ---------------- workspace layout (float offsets), total 77,794,496 f = 311.18 MB ----
static constexpr size_t OFF_QKV    = 0;                                  // [N][768] f32
// union region: BBUF [256][1280] f32 (dead after conv_B)  OR  CSR arrays
static constexpr size_t OFF_UNION  = OFF_QKV + (size_t)NN * 768;
static constexpr size_t OFF_BBUF   = OFF_UNION;                          // 327,680 floats
static constexpr size_t OFF_ROWPTR = OFF_UNION;                          // [N] int
static constexpr size_t OFF_CURSOR = OFF_ROWPTR + NN;                    // [N] int
static constexpr size_t OFF_SRCS   = OFF_CURSOR + NN;                    // [E] int
static constexpr size_t OFF_BIAS   = OFF_UNION + 600000;                 // [1280] f32
static constexpr size_t OFF_BT     = OFF_BIAS + 1280;                    // [1536][512] bf16 = 393,216 f
static constexpr size_t OFF_END    = OFF_BT + (size_t)1536 * 512 / 2;

using bf16x8 = __attribute__((ext_vector_type(8))) __bf16;
using f32x4v = __attribute__((ext_vector_type(4))) float;
using u32x4  = __attribute__((ext_vector_type(4))) unsigned int;

static __device__ inline unsigned int bf_bits(__bf16 b) {
    union { __bf16 b; unsigned short u; } x; x.b = b; return (unsigned int)x.u;
}

// ---------------- zero fill ----------------
__global__ __launch_bounds__(256)
void zero_kernel(float4* __restrict__ p, long n4)
{
    const long stride = (long)gridDim.x * blockDim.x;
    for (long i = (long)blockIdx.x * blockDim.x + threadIdx.x; i < n4; i += stride)
        p[i] = make_float4(0.f, 0.f, 0.f, 0.f);
}

// ---------------- fused weight build (f32, into union BBUF) ----------------
__global__ __launch_bounds__(256)
void build_B_kernel(const float* __restrict__ Wk, const float* __restrict__ Wq,
                    const float* __restrict__ Wv,
                    const float* __restrict__ bk, const float* __restrict__ bq,
                    const float* __restrict__ bv,
                    const float* __restrict__ rel_att, const float* __restrict__ rel_msg,
                    float* __restrict__ Bbuf, float* __restrict__ biasbuf)
{
    const int din = blockIdx.x;   // 0..255 (input dim)
    const int t   = threadIdx.x;  // 0..255 (output col within segment)
    __shared__ float wk[256], wv[256];
    wk[t] = Wk[din * 256 + t];
    wv[t] = Wv[din * 256 + t];
    __syncthreads();
    const int h = t >> 5, e = t & 31;
    Bbuf[(size_t)din * 1280 + t] = Wq[din * 256 + t];
    #pragma unroll
    for (int r = 0; r < 2; ++r) {
        const float* ra = rel_att + (size_t)((r * 8 + h) * 32) * 32 + e;
        const float* rm = rel_msg + (size_t)((r * 8 + h) * 32) * 32 + e;
        float sa = 0.f, sm = 0.f;
        #pragma unroll
        for (int dd = 0; dd < 32; ++dd) {
            sa = fmaf(wk[h * 32 + dd], ra[dd * 32], sa);
            sm = fmaf(wv[h * 32 + dd], rm[dd * 32], sm);
        }
        Bbuf[(size_t)din * 1280 + 256 + r * 512 + t]       = sa;
        Bbuf[(size_t)din * 1280 + 256 + r * 512 + 256 + t] = sm;
    }
    if (din == 0) {
        biasbuf[t] = bq[t];
        #pragma unroll
        for (int r = 0; r < 2; ++r) {
            float sa = 0.f, sm = 0.f;
            #pragma unroll
            for (int dd = 0; dd < 32; ++dd) {
                sa = fmaf(bk[h * 32 + dd], rel_att[(size_t)((r * 8 + h) * 32 + dd) * 32 + e], sa);
                sm = fmaf(bv[h * 32 + dd], rel_msg[(size_t)((r * 8 + h) * 32 + dd) * 32 + e], sm);
            }
            biasbuf[256 + r * 512 + t]       = sa;
            biasbuf[256 + r * 512 + 256 + t] = sm;
        }
    }
}

// BBUF [256][1280] + Wa [256][256] -> BT [1536][512] bf16 bits (n-major; hi k0..255 | lo)
__global__ __launch_bounds__(256)
void conv_B_kernel(const float* __restrict__ Bbuf, const float* __restrict__ Wa,
                   unsigned short* __restrict__ BT)
{
    const int n = blockIdx.x;    // 0..1535
    const int k = threadIdx.x;   // 0..255
    const float v = (n < 1280) ? Bbuf[(size_t)k * 1280 + n]
                               : Wa[(size_t)k * 256 + (n - 1280)];
    __bf16 hi = (__bf16)v;
    __bf16 lo = (__bf16)(v - (float)hi);
    BT[(size_t)n * 512 + k]       = (unsigned short)bf_bits(hi);
    BT[(size_t)n * 512 + 256 + k] = (unsigned short)bf_bits(lo);
}

// ---------------- split-bf16 MFMA GEMM, in-kernel A conversion ----------------
// C[M][ldc] = alpha*(A_f32[M][256] @ B) + bias, B given as BT [Nc][512] bf16
// (hi|lo, n-major, pre-offset). 128x128 tile, 4 waves (2x2), 8 chunks of 32
// f32-k, 3 terms/chunk: AhiBhi + AloBhi + AhiBlo. LDS [128][64] bf16 per
// operand (cols 0..31 = hi chunk, 32..63 = lo chunk), XOR swizzle (row&7)<<4.
__global__ __launch_bounds__(256)
void gemm_mfma(const float* __restrict__ A, int lda,
               const unsigned short* __restrict__ BT,
               const float* __restrict__ bias,
               float* __restrict__ C, int ldc,
               int M, float alpha)
{
    __shared__ __align__(16) unsigned short AsB[128 * 64];
    __shared__ __align__(16) unsigned short BsB[128 * 64];
    const int tid = threadIdx.x;
    const int bm = blockIdx.x * 128;
    const int bn = blockIdx.y * 128;
    const int wid = tid >> 6;
    const int l   = tid & 63;
    const int wm  = (wid >> 1) * 64;
    const int wn  = (wid & 1) * 64;
    const int l15 = l & 15;
    const int k8  = (l >> 4) * 8;   // f32-k offset within chunk (0,8,16,24)

    f32x4v acc[4][4];
    #pragma unroll
    for (int i = 0; i < 4; ++i)
        #pragma unroll
        for (int j = 0; j < 4; ++j)
            acc[i][j] = (f32x4v){0.f, 0.f, 0.f, 0.f};

    float4 rA[2][2];   // 2 slots x 8 consecutive f32
    u32x4  rB[4];      // 4 slots x 16 B

    auto g_load = [&](int kb) {
        #pragma unroll
        for (int it = 0; it < 2; ++it) {
            const int s = it * 256 + tid;        // 0..511
            const int row = s >> 2, c8 = (s & 3) * 8;
            const float* base = A + (size_t)(bm + row) * lda + kb * 32 + c8;
            const bool ok = (bm + row) < M;
            rA[it][0] = ok ? *reinterpret_cast<const float4*>(base)     : make_float4(0,0,0,0);
            rA[it][1] = ok ? *reinterpret_cast<const float4*>(base + 4) : make_float4(0,0,0,0);
        }
        #pragma unroll
        for (int it = 0; it < 4; ++it) {
            const int s = it * 256 + tid;        // 0..1023
            const int row = s >> 3, q = s & 7;   // q 0..3 = hi 16B seg, 4..7 = lo
            const char* src = reinterpret_cast<const char*>(BT) + (size_t)(bn + row) * 1024
                              + ((q < 4) ? (kb * 64 + q * 16) : (512 + kb * 64 + (q - 4) * 16));
            rB[it] = *reinterpret_cast<const u32x4*>(src);
        }
    };

    g_load(0);

    for (int kb = 0; kb < 8; ++kb) {
        __syncthreads();   // previous chunk's fragment reads done
        // A: convert f32 -> hi/lo bf16, write both 16B segments
        #pragma unroll
        for (int it = 0; it < 2; ++it) {
            const int s = it * 256 + tid;
            const int row = s >> 2, c8 = (s & 3) * 8;
            float vv[8] = {rA[it][0].x, rA[it][0].y, rA[it][0].z, rA[it][0].w,
                           rA[it][1].x, rA[it][1].y, rA[it][1].z, rA[it][1].w};
            unsigned int hw[4], lw[4];
            #pragma unroll
            for (int j = 0; j < 4; ++j) {
                const __bf16 h0 = (__bf16)vv[2*j],  h1 = (__bf16)vv[2*j+1];
                const float  r0 = vv[2*j] - (float)h0, r1 = vv[2*j+1] - (float)h1;
                const __bf16 l0 = (__bf16)r0, l1 = (__bf16)r1;
                hw[j] = bf_bits(h0) | (bf_bits(h1) << 16);
                lw[j] = bf_bits(l0) | (bf_bits(l1) << 16);
            }
            const int swz = (row & 7) << 4;
            char* basep = reinterpret_cast<char*>(AsB);
            *reinterpret_cast<u32x4*>(basep + ((row * 128 +      c8 * 2) ^ swz)) = (u32x4){hw[0],hw[1],hw[2],hw[3]};
            *reinterpret_cast<u32x4*>(basep + ((row * 128 + 64 + c8 * 2) ^ swz)) = (u32x4){lw[0],lw[1],lw[2],lw[3]};
        }
        // B: raw bf16 copy
        #pragma unroll
        for (int it = 0; it < 4; ++it) {
            const int s = it * 256 + tid;
            const int row = s >> 3, q = s & 7;
            const int swz = (row & 7) << 4;
            *reinterpret_cast<u32x4*>(reinterpret_cast<char*>(BsB) + ((row * 128 + q * 16) ^ swz)) = rB[it];
        }
        __syncthreads();
        if (kb < 7) g_load(kb + 1);   // overlap next chunk's global loads with MFMA

        #pragma unroll
        for (int term = 0; term < 3; ++term) {
            const int apart = (term == 1) ? 64 : 0;   // term1: A-lo
            const int bpart = (term == 2) ? 64 : 0;   // term2: B-lo
            bf16x8 af[4], bfr[4];
            #pragma unroll
            for (int i = 0; i < 4; ++i) {
                const int arow = wm + i * 16 + l15;
                af[i]  = *reinterpret_cast<const bf16x8*>(reinterpret_cast<const char*>(AsB)
                           + ((arow * 128 + apart + k8 * 2) ^ ((arow & 7) << 4)));
                const int brow = wn + i * 16 + l15;
                bfr[i] = *reinterpret_cast<const bf16x8*>(reinterpret_cast<const char*>(BsB)
                           + ((brow * 128 + bpart + k8 * 2) ^ ((brow & 7) << 4)));
            }
            #pragma unroll
            for (int i = 0; i < 4; ++i)
                #pragma unroll
                for (int j = 0; j < 4; ++j)
                    acc[i][j] = __builtin_amdgcn_mfma_f32_16x16x32_bf16(af[i], bfr[j], acc[i][j], 0, 0, 0);
        }
    }

    // epilogue: C/D layout col=lane&15, row=(lane>>4)*4+reg (m89-verified)
    #pragma unroll
    for (int i = 0; i < 4; ++i) {
        const int rbase = bm + wm + i * 16 + (l >> 4) * 4;
        #pragma unroll
        for (int j = 0; j < 4; ++j) {
            const int col = bn + wn + j * 16 + l15;
            const float bcol = bias[col];
            #pragma unroll
            for (int r = 0; r < 4; ++r) {
                const int row = rbase + r;
                if (row < M)
                    C[(size_t)row * ldc + col] = alpha * acc[i][j][r] + bcol;
            }
        }
    }
}

// ---------------- CSR build ----------------
__global__ __launch_bounds__(256)
void hist_kernel(const int* __restrict__ dst, int* __restrict__ deg, int E)
{
    const int stride = gridDim.x * blockDim.x;
    for (int e = blockIdx.x * blockDim.x + threadIdx.x; e < E; e += stride)
        atomicAdd(&deg[dst[e]], 1);
}

// in-place capable: deg may alias cursor (reads complete before writes)
__global__ __launch_bounds__(1024)
void scan_kernel(const int* __restrict__ deg, int* __restrict__ rowptr,
                 int* __restrict__ cursor, int n)
{
    __shared__ int sm[1024];
    __shared__ int carry_s;
    const int tid = threadIdx.x;
    if (tid == 0) carry_s = 0;
    __syncthreads();
    for (int base = 0; base < n; base += 1024) {
        const int i = base + tid;
        const int v = (i < n) ? deg[i] : 0;
        sm[tid] = v;
        __syncthreads();
        for (int off = 1; off < 1024; off <<= 1) {
            int add = (tid >= off) ? sm[tid - off] : 0;
            __syncthreads();
            sm[tid] += add;
            __syncthreads();
        }
        const int excl = sm[tid] - v + carry_s;
        if (i < n) { rowptr[i] = excl; cursor[i] = excl; }
        __syncthreads();
        if (tid == 0) carry_s += sm[1023];
        __syncthreads();
    }
}

__global__ __launch_bounds__(256)
void scatter_kernel(const int* __restrict__ src, const int* __restrict__ dst,
                    int* __restrict__ cursor, int* __restrict__ srcs, int E)
{
    const int stride = gridDim.x * blockDim.x;
    for (int e = blockIdx.x * blockDim.x + threadIdx.x; e < E; e += stride) {
        int pos = atomicAdd(&cursor[dst[e]], 1);
        srcs[pos] = src[e];
    }
}

// ---------------- fused online-softmax aggregation: one wave per node ----------------
__global__ __launch_bounds__(256)
void node_agg_kernel(const float* __restrict__ QKV,
                     const int* __restrict__ rowptr, const int* __restrict__ endptr,
                     const int* __restrict__ srcs,
                     const float* __restrict__ pri8,
                     float* __restrict__ AGG, int accumulate)
{
    const int node = (blockIdx.x * blockDim.x + threadIdx.x) >> 6;
    if (node >= NN) return;
    const int l = threadIdx.x & 63;
    const int h = l >> 3;
    const float4 q4 = reinterpret_cast<const float4*>(QKV + (size_t)node * 768)[l];
    const float prh = pri8[h] * INV_SQRT_DK;
    const int s0 = rowptr[node];
    const int s1 = endptr[node];
    float m = -3.0e38f, den = 0.f;
    float4 acc = make_float4(0.f, 0.f, 0.f, 0.f);
    for (int i = s0; i < s1; ++i) {
        const int s = srcs[i];
        const float4* row = reinterpret_cast<const float4*>(QKV + (size_t)s * 768);
        const float4 k4 = row[64 + l];
        float p = q4.x * k4.x + q4.y * k4.y + q4.z * k4.z + q4.w * k4.w;
        p += __shfl_xor(p, 1, 64);
        p += __shfl_xor(p, 2, 64);
        p += __shfl_xor(p, 4, 64);
        const float sc = p * prh;
        const float mnew = fmaxf(m, sc);
        const float scale = __expf(m - mnew);
        const float ex = __expf(sc - mnew);
        const float4 v4 = row[128 + l];
        den = den * scale + ex;
        acc.x = acc.x * scale + v4.x * ex;
        acc.y = acc.y * scale + v4.y * ex;
        acc.z = acc.z * scale + v4.z * ex;
        acc.w = acc.w * scale + v4.w * ex;
        m = mnew;
    }
    const float inv = (s1 > s0) ? 1.0f / den : 0.f;
    float4 o = make_float4(acc.x * inv, acc.y * inv, acc.z * inv, acc.w * inv);
    float4* outp = reinterpret_cast<float4*>(AGG + (size_t)node * 256);
    if (accumulate) {
        const float4 prev = outp[l];
        o.x += prev.x; o.y += prev.y; o.z += prev.z; o.w += prev.w;
    }
    outp[l] = o;
}

// ---------------- residual + LayerNorm ----------------
__global__ __launch_bounds__(256)
void ln_kernel(const float* __restrict__ tmp, const float* __restrict__ hres,
               const float* __restrict__ g, const float* __restrict__ b,
               float* __restrict__ out, int M)
{
    const int gtid = blockIdx.x * blockDim.x + threadIdx.x;
    const int wid = gtid >> 6;
    const int nw = (gridDim.x * blockDim.x) >> 6;
    const int lane = threadIdx.x & 63;
    const float4 gv = reinterpret_cast<const float4*>(g)[lane];
    const float4 bv = reinterpret_cast<const float4*>(b)[lane];
    for (int row = wid; row < M; row += nw) {
        const float4 tv = reinterpret_cast<const float4*>(tmp + (size_t)row * 256)[lane];
        const float4 hv = reinterpret_cast<const float4*>(hres + (size_t)row * 256)[lane];
        float y0 = tv.x + hv.x, y1 = tv.y + hv.y, y2 = tv.z + hv.z, y3 = tv.w + hv.w;
        float ssum = y0 + y1 + y2 + y3;
        #pragma unroll
        for (int off = 32; off; off >>= 1) ssum += __shfl_xor(ssum, off, 64);
        const float mean = ssum * (1.f / 256.f);
        const float d0 = y0 - mean, d1 = y1 - mean, d2 = y2 - mean, d3 = y3 - mean;
        float sq = d0 * d0 + d1 * d1 + d2 * d2 + d3 * d3;
        #pragma unroll
        for (int off = 32; off; off >>= 1) sq += __shfl_xor(sq, off, 64);
        const float inv = rsqrtf(sq * (1.f / 256.f) + 1e-5f);
        float4 o;
        o.x = d0 * inv * gv.x + bv.x;
        o.y = d1 * inv * gv.y + bv.y;
        o.z = d2 * inv * gv.z + bv.z;
        o.w = d3 * inv * gv.w + bv.w;
        reinterpret_cast<float4*>(out + (size_t)row * 256)[lane] = o;
    }
}

extern "C" void kernel_launch(void* const* d_in, const int* in_sizes, int n_in,
                              void* d_out, int out_size, void* d_ws, size_t ws_size,
                              hipStream_t stream)
{
    const float* h    = (const float*)d_in[0];
    const int* src0   = (const int*)d_in[1];
    const int* dst0   = (const int*)d_in[2];
    const int* src1   = (const int*)d_in[3];
    const int* dst1   = (const int*)d_in[4];
    const float* Wk   = (const float*)d_in[5];
    const float* bk   = (const float*)d_in[6];
    const float* Wq   = (const float*)d_in[7];
    const float* bq   = (const float*)d_in[8];
    const float* Wv   = (const float*)d_in[9];
    const float* bv   = (const float*)d_in[10];
    const float* Wa   = (const float*)d_in[11];
    const float* ba   = (const float*)d_in[12];
    const float* lng  = (const float*)d_in[13];
    const float* lnb  = (const float*)d_in[14];
    const float* rel_pri = (const float*)d_in[15];
    const float* rel_att = (const float*)d_in[16];
    const float* rel_msg = (const float*)d_in[17];

    float* ws    = (float*)d_ws;
    float* QKV   = ws + OFF_QKV;
    float* BBUF  = ws + OFF_BBUF;     // aliases CSR region (dead after conv_B)
    float* BIAS  = ws + OFF_BIAS;
    int* ROWPTR  = (int*)(ws + OFF_ROWPTR);
    int* CURSOR  = (int*)(ws + OFF_CURSOR);
    int* SRCS    = (int*)(ws + OFF_SRCS);
    unsigned short* BT = (unsigned short*)(ws + OFF_BT);
    float* AGG   = (float*)d_out;     // scratch until final LN
    float* TMP   = ws + OFF_QKV;      // GEMM3 output aliases dead QKV

    // fused weights -> BBUF/BIAS, then bf16 split-transpose -> BT (BBUF dies here)
    build_B_kernel<<<256, 256, 0, stream>>>(Wk, Wq, Wv, bk, bq, bv,
                                            rel_att, rel_msg, BBUF, BIAS);
    conv_B_kernel<<<1536, 256, 0, stream>>>(BBUF, Wa, BT);

    // GEMM1: [N,256] x [256,768] -> q | kr0 | vr0
    {
        dim3 grid((NN + 127) / 128, 768 / 128);
        gemm_mfma<<<grid, 256, 0, stream>>>(h, 256, BT, BIAS, QKV, 768, NN, 1.0f);
    }
    // relation 0: CSR (overwrites BBUF region) + fused aggregation
    zero_kernel<<<128, 256, 0, stream>>>((float4*)CURSOR, (long)NN / 4);
    hist_kernel<<<1024, 256, 0, stream>>>(dst0, CURSOR, EE);
    scan_kernel<<<1, 1024, 0, stream>>>(CURSOR, ROWPTR, CURSOR, NN);
    scatter_kernel<<<1024, 256, 0, stream>>>(src0, dst0, CURSOR, SRCS, EE);
    node_agg_kernel<<<NN * 64 / 256, 256, 0, stream>>>(QKV, ROWPTR, CURSOR, SRCS,
                                                       rel_pri + 0, AGG, 0);

    // GEMM2: [N,256] x [256,512] -> kr1 | vr1 (q kept)
    {
        dim3 grid((NN + 127) / 128, 512 / 128);
        gemm_mfma<<<grid, 256, 0, stream>>>(h, 256, BT + (size_t)768 * 512, BIAS + 768,
                                            QKV + 256, 768, NN, 1.0f);
    }
    // relation 1
    zero_kernel<<<128, 256, 0, stream>>>((float4*)CURSOR, (long)NN / 4);
    hist_kernel<<<1024, 256, 0, stream>>>(dst1, CURSOR, EE);
    scan_kernel<<<1, 1024, 0, stream>>>(CURSOR, ROWPTR, CURSOR, NN);
    scatter_kernel<<<1024, 256, 0, stream>>>(src1, dst1, CURSOR, SRCS, EE);
    node_agg_kernel<<<NN * 64 / 256, 256, 0, stream>>>(QKV, ROWPTR, CURSOR, SRCS,
                                                       rel_pri + 8, AGG, 1);

    // GEMM3: tmp = 0.5*(agg @ Wa) + ba
    {
        dim3 grid((NN + 127) / 128, 256 / 128);
        gemm_mfma<<<grid, 256, 0, stream>>>(AGG, 256, BT + (size_t)1280 * 512, ba,
                                            TMP, 256, NN, 0.5f);
    }
    // residual + layernorm
    ln_kernel<<<2048, 256, 0, stream>>>(TMP, h, lng, lnb, (float*)d_out, NN);
}

// Round 7
// 1075.290 us; speedup vs baseline: 2.2179x; 1.3340x over previous
//
#include <hip/hip_runtime.h>
#include <cstdint>
#include <cstddef>

// HGT layer: N=100000, E=400000/rel, D=256, H=8, DK=32, R=2.
// Round 7:
//  - ONE fused projection GEMM [N,256]x[256,1280] -> q(f32) | kr0|vr0|kr1|vr1 (bf16),
//    grid transposed (blockIdx.x = N-tile) so A is fetched ~once.
//  - node_agg gathers bf16 K/V (1 KB/edge instead of 2 KB).
//  - CSR scan: hierarchical 3-kernel (was 150-200us single-block -> ~10us).
//  - split-bf16 MFMA (3-term) for both GEMMs; ws layout identical size to
//    round 6 (311.18 MB proven good); PART aliases SRCS[0..97].

#define NN 100000
#define EE 400000

static constexpr float INV_SQRT_DK = 0.17677669529663687f; // 1/sqrt(32)

// ---------------- workspace layout (float offsets), total 77,794,496 f = 311.18 MB ----
static constexpr size_t OFF_Q      = 0;                                  // [N][256] f32
static constexpr size_t OFF_KV     = OFF_Q + (size_t)NN * 256;           // [N][1024] bf16 (kr0|vr0|kr1|vr1)
static constexpr size_t OFF_UNION  = OFF_KV + (size_t)NN * 512;          // (bf16 = 512 f-equiv/row)
static constexpr size_t OFF_BBUF   = OFF_UNION;                          // [256][1280] f32 (dead after conv_B)
static constexpr size_t OFF_ROWPTR = OFF_UNION;                          // [N] int
static constexpr size_t OFF_CURSOR = OFF_ROWPTR + NN;                    // [N] int
static constexpr size_t OFF_SRCS   = OFF_CURSOR + NN;                    // [E] int (PART aliases first 1024)
static constexpr size_t OFF_BIAS   = OFF_UNION + 600000;                 // [1280] f32
static constexpr size_t OFF_BT     = OFF_BIAS + 1280;                    // [1536][512] bf16
static constexpr size_t OFF_END    = OFF_BT + (size_t)1536 * 512 / 2;

using bf16x8 = __attribute__((ext_vector_type(8))) __bf16;
using f32x4v = __attribute__((ext_vector_type(4))) float;
using u32x4  = __attribute__((ext_vector_type(4))) unsigned int;

static __device__ inline unsigned int bf_bits(__bf16 b) {
    union { __bf16 b; unsigned short u; } x; x.b = b; return (unsigned int)x.u;
}
static __device__ inline float bf2f(unsigned short u) {
    union { unsigned int u; float f; } x; x.u = ((unsigned int)u) << 16; return x.f;
}

// ---------------- zero fill ----------------
__global__ __launch_bounds__(256)
void zero_kernel(float4* __restrict__ p, long n4)
{
    const long stride = (long)gridDim.x * blockDim.x;
    for (long i = (long)blockIdx.x * blockDim.x + threadIdx.x; i < n4; i += stride)
        p[i] = make_float4(0.f, 0.f, 0.f, 0.f);
}

// ---------------- fused weight build (f32, into union BBUF) ----------------
__global__ __launch_bounds__(256)
void build_B_kernel(const float* __restrict__ Wk, const float* __restrict__ Wq,
                    const float* __restrict__ Wv,
                    const float* __restrict__ bk, const float* __restrict__ bq,
                    const float* __restrict__ bv,
                    const float* __restrict__ rel_att, const float* __restrict__ rel_msg,
                    float* __restrict__ Bbuf, float* __restrict__ biasbuf)
{
    const int din = blockIdx.x;   // 0..255 (input dim)
    const int t   = threadIdx.x;  // 0..255
    __shared__ float wk[256], wv[256];
    wk[t] = Wk[din * 256 + t];
    wv[t] = Wv[din * 256 + t];
    __syncthreads();
    const int h = t >> 5, e = t & 31;
    Bbuf[(size_t)din * 1280 + t] = Wq[din * 256 + t];
    #pragma unroll
    for (int r = 0; r < 2; ++r) {
        const float* ra = rel_att + (size_t)((r * 8 + h) * 32) * 32 + e;
        const float* rm = rel_msg + (size_t)((r * 8 + h) * 32) * 32 + e;
        float sa = 0.f, sm = 0.f;
        #pragma unroll
        for (int dd = 0; dd < 32; ++dd) {
            sa = fmaf(wk[h * 32 + dd], ra[dd * 32], sa);
            sm = fmaf(wv[h * 32 + dd], rm[dd * 32], sm);
        }
        Bbuf[(size_t)din * 1280 + 256 + r * 512 + t]       = sa;
        Bbuf[(size_t)din * 1280 + 256 + r * 512 + 256 + t] = sm;
    }
    if (din == 0) {
        biasbuf[t] = bq[t];
        #pragma unroll
        for (int r = 0; r < 2; ++r) {
            float sa = 0.f, sm = 0.f;
            #pragma unroll
            for (int dd = 0; dd < 32; ++dd) {
                sa = fmaf(bk[h * 32 + dd], rel_att[(size_t)((r * 8 + h) * 32 + dd) * 32 + e], sa);
                sm = fmaf(bv[h * 32 + dd], rel_msg[(size_t)((r * 8 + h) * 32 + dd) * 32 + e], sm);
            }
            biasbuf[256 + r * 512 + t]       = sa;
            biasbuf[256 + r * 512 + 256 + t] = sm;
        }
    }
}

// BBUF [256][1280] + Wa [256][256] -> BT [1536][512] bf16 (n-major; hi|lo)
__global__ __launch_bounds__(256)
void conv_B_kernel(const float* __restrict__ Bbuf, const float* __restrict__ Wa,
                   unsigned short* __restrict__ BT)
{
    const int n = blockIdx.x;    // 0..1535
    const int k = threadIdx.x;   // 0..255
    const float v = (n < 1280) ? Bbuf[(size_t)k * 1280 + n]
                               : Wa[(size_t)k * 256 + (n - 1280)];
    __bf16 hi = (__bf16)v;
    __bf16 lo = (__bf16)(v - (float)hi);
    BT[(size_t)n * 512 + k]       = (unsigned short)bf_bits(hi);
    BT[(size_t)n * 512 + 256 + k] = (unsigned short)bf_bits(lo);
}

// ---------------- split-bf16 MFMA GEMM, in-kernel A conversion ----------------
// blockIdx.x = N-tile (fast -> A-tile reuse across concurrent blocks),
// blockIdx.y = M-tile. Output: cols < 256 -> f32 into Qout (ld 256);
// cols >= 256 -> bf16 into KVout (ld 1024, col-256).
__global__ __launch_bounds__(256)
void gemm_mfma(const float* __restrict__ A, int lda,
               const unsigned short* __restrict__ BT,
               const float* __restrict__ bias,
               float* __restrict__ Qout, unsigned short* __restrict__ KVout,
               int M, float alpha)
{
    __shared__ __align__(16) unsigned short AsB[128 * 64];
    __shared__ __align__(16) unsigned short BsB[128 * 64];
    const int tid = threadIdx.x;
    const int bn = blockIdx.x * 128;
    const int bm = blockIdx.y * 128;
    const int wid = tid >> 6;
    const int l   = tid & 63;
    const int wm  = (wid >> 1) * 64;
    const int wn  = (wid & 1) * 64;
    const int l15 = l & 15;
    const int k8  = (l >> 4) * 8;

    f32x4v acc[4][4];
    #pragma unroll
    for (int i = 0; i < 4; ++i)
        #pragma unroll
        for (int j = 0; j < 4; ++j)
            acc[i][j] = (f32x4v){0.f, 0.f, 0.f, 0.f};

    float4 rA[2][2];
    u32x4  rB[4];

    auto g_load = [&](int kb) {
        #pragma unroll
        for (int it = 0; it < 2; ++it) {
            const int s = it * 256 + tid;
            const int row = s >> 2, c8 = (s & 3) * 8;
            const float* base = A + (size_t)(bm + row) * lda + kb * 32 + c8;
            const bool ok = (bm + row) < M;
            rA[it][0] = ok ? *reinterpret_cast<const float4*>(base)     : make_float4(0,0,0,0);
            rA[it][1] = ok ? *reinterpret_cast<const float4*>(base + 4) : make_float4(0,0,0,0);
        }
        #pragma unroll
        for (int it = 0; it < 4; ++it) {
            const int s = it * 256 + tid;
            const int row = s >> 3, q = s & 7;
            const char* src = reinterpret_cast<const char*>(BT) + (size_t)(bn + row) * 1024
                              + ((q < 4) ? (kb * 64 + q * 16) : (512 + kb * 64 + (q - 4) * 16));
            rB[it] = *reinterpret_cast<const u32x4*>(src);
        }
    };

    g_load(0);

    for (int kb = 0; kb < 8; ++kb) {
        __syncthreads();
        #pragma unroll
        for (int it = 0; it < 2; ++it) {
            const int s = it * 256 + tid;
            const int row = s >> 2, c8 = (s & 3) * 8;
            float vv[8] = {rA[it][0].x, rA[it][0].y, rA[it][0].z, rA[it][0].w,
                           rA[it][1].x, rA[it][1].y, rA[it][1].z, rA[it][1].w};
            unsigned int hw[4], lw[4];
            #pragma unroll
            for (int j = 0; j < 4; ++j) {
                const __bf16 h0 = (__bf16)vv[2*j],  h1 = (__bf16)vv[2*j+1];
                const float  r0 = vv[2*j] - (float)h0, r1 = vv[2*j+1] - (float)h1;
                const __bf16 l0 = (__bf16)r0, l1 = (__bf16)r1;
                hw[j] = bf_bits(h0) | (bf_bits(h1) << 16);
                lw[j] = bf_bits(l0) | (bf_bits(l1) << 16);
            }
            const int swz = (row & 7) << 4;
            char* basep = reinterpret_cast<char*>(AsB);
            *reinterpret_cast<u32x4*>(basep + ((row * 128 +      c8 * 2) ^ swz)) = (u32x4){hw[0],hw[1],hw[2],hw[3]};
            *reinterpret_cast<u32x4*>(basep + ((row * 128 + 64 + c8 * 2) ^ swz)) = (u32x4){lw[0],lw[1],lw[2],lw[3]};
        }
        #pragma unroll
        for (int it = 0; it < 4; ++it) {
            const int s = it * 256 + tid;
            const int row = s >> 3, q = s & 7;
            const int swz = (row & 7) << 4;
            *reinterpret_cast<u32x4*>(reinterpret_cast<char*>(BsB) + ((row * 128 + q * 16) ^ swz)) = rB[it];
        }
        __syncthreads();
        if (kb < 7) g_load(kb + 1);

        #pragma unroll
        for (int term = 0; term < 3; ++term) {
            const int apart = (term == 1) ? 64 : 0;
            const int bpart = (term == 2) ? 64 : 0;
            bf16x8 af[4], bfr[4];
            #pragma unroll
            for (int i = 0; i < 4; ++i) {
                const int arow = wm + i * 16 + l15;
                af[i]  = *reinterpret_cast<const bf16x8*>(reinterpret_cast<const char*>(AsB)
                           + ((arow * 128 + apart + k8 * 2) ^ ((arow & 7) << 4)));
                const int brow = wn + i * 16 + l15;
                bfr[i] = *reinterpret_cast<const bf16x8*>(reinterpret_cast<const char*>(BsB)
                           + ((brow * 128 + bpart + k8 * 2) ^ ((brow & 7) << 4)));
            }
            #pragma unroll
            for (int i = 0; i < 4; ++i)
                #pragma unroll
                for (int j = 0; j < 4; ++j)
                    acc[i][j] = __builtin_amdgcn_mfma_f32_16x16x32_bf16(af[i], bfr[j], acc[i][j], 0, 0, 0);
        }
    }

    // epilogue: C/D layout col=lane&15, row=(lane>>4)*4+reg (m89-verified)
    const bool q_seg = (bn < 256);
    #pragma unroll
    for (int i = 0; i < 4; ++i) {
        const int rbase = bm + wm + i * 16 + (l >> 4) * 4;
        #pragma unroll
        for (int j = 0; j < 4; ++j) {
            const int col = bn + wn + j * 16 + l15;
            const float bcol = bias[col];
            #pragma unroll
            for (int r = 0; r < 4; ++r) {
                const int row = rbase + r;
                if (row < M) {
                    const float o = alpha * acc[i][j][r] + bcol;
                    if (q_seg)
                        Qout[(size_t)row * 256 + col] = o;
                    else
                        KVout[(size_t)row * 1024 + (col - 256)] = (unsigned short)bf_bits((__bf16)o);
                }
            }
        }
    }
}

// ---------------- CSR build ----------------
__global__ __launch_bounds__(256)
void hist_kernel(const int* __restrict__ dst, int* __restrict__ deg, int E)
{
    const int stride = gridDim.x * blockDim.x;
    for (int e = blockIdx.x * blockDim.x + threadIdx.x; e < E; e += stride)
        atomicAdd(&deg[dst[e]], 1);
}

// hierarchical scan: (1) per-block excl scan + block total
__global__ __launch_bounds__(1024)
void scan1_kernel(const int* __restrict__ deg, int* __restrict__ rowptr,
                  int* __restrict__ part, int n)
{
    __shared__ int sm[1024];
    const int tid = threadIdx.x;
    const int i = blockIdx.x * 1024 + tid;
    const int v = (i < n) ? deg[i] : 0;
    sm[tid] = v;
    __syncthreads();
    for (int off = 1; off < 1024; off <<= 1) {
        int add = (tid >= off) ? sm[tid - off] : 0;
        __syncthreads();
        sm[tid] += add;
        __syncthreads();
    }
    if (i < n) rowptr[i] = sm[tid] - v;
    if (tid == 1023) part[blockIdx.x] = sm[1023];
}

// (2) exclusive scan of partials (np <= 1024), single block
__global__ __launch_bounds__(1024)
void scan2_kernel(int* __restrict__ part, int np)
{
    __shared__ int sm[1024];
    const int tid = threadIdx.x;
    const int v = (tid < np) ? part[tid] : 0;
    sm[tid] = v;
    __syncthreads();
    for (int off = 1; off < 1024; off <<= 1) {
        int add = (tid >= off) ? sm[tid - off] : 0;
        __syncthreads();
        sm[tid] += add;
        __syncthreads();
    }
    if (tid < np) part[tid] = sm[tid] - v;
}

// (3) add block offsets; emit rowptr + cursor
__global__ __launch_bounds__(256)
void scan3_kernel(int* __restrict__ rowptr, int* __restrict__ cursor,
                  const int* __restrict__ part, int n)
{
    const int i = blockIdx.x * 256 + threadIdx.x;
    if (i < n) {
        const int r = rowptr[i] + part[i >> 10];
        rowptr[i] = r;
        cursor[i] = r;
    }
}

__global__ __launch_bounds__(256)
void scatter_kernel(const int* __restrict__ src, const int* __restrict__ dst,
                    int* __restrict__ cursor, int* __restrict__ srcs, int E)
{
    const int stride = gridDim.x * blockDim.x;
    for (int e = blockIdx.x * blockDim.x + threadIdx.x; e < E; e += stride) {
        int pos = atomicAdd(&cursor[dst[e]], 1);
        srcs[pos] = src[e];
    }
}

// ---------------- fused online-softmax aggregation (bf16 K/V) ----------------
// one wave per node; lane l: head h=l>>3, owns dims [4l,4l+4).
__global__ __launch_bounds__(256)
void node_agg_kernel(const float* __restrict__ Q, const unsigned short* __restrict__ KV,
                     int roff,   // 0 for rel0, 512 for rel1
                     const int* __restrict__ rowptr, const int* __restrict__ endptr,
                     const int* __restrict__ srcs,
                     const float* __restrict__ pri8,
                     float* __restrict__ AGG, int accumulate)
{
    const int node = (blockIdx.x * blockDim.x + threadIdx.x) >> 6;
    if (node >= NN) return;
    const int l = threadIdx.x & 63;
    const int h = l >> 3;
    const float4 q4 = reinterpret_cast<const float4*>(Q + (size_t)node * 256)[l];
    const float prh = pri8[h] * INV_SQRT_DK;
    const int s0 = rowptr[node];
    const int s1 = endptr[node];
    float m = -3.0e38f, den = 0.f;
    float4 acc = make_float4(0.f, 0.f, 0.f, 0.f);
    for (int i = s0; i < s1; ++i) {
        const int s = srcs[i];
        const unsigned short* kvrow = KV + (size_t)s * 1024 + roff;
        const ushort4 k4 = *reinterpret_cast<const ushort4*>(kvrow + l * 4);
        float p = q4.x * bf2f(k4.x) + q4.y * bf2f(k4.y) + q4.z * bf2f(k4.z) + q4.w * bf2f(k4.w);
        p += __shfl_xor(p, 1, 64);
        p += __shfl_xor(p, 2, 64);
        p += __shfl_xor(p, 4, 64);
        const float sc = p * prh;
        const float mnew = fmaxf(m, sc);
        const float scale = __expf(m - mnew);
        const float ex = __expf(sc - mnew);
        const ushort4 v4 = *reinterpret_cast<const ushort4*>(kvrow + 256 + l * 4);
        den = den * scale + ex;
        acc.x = acc.x * scale + bf2f(v4.x) * ex;
        acc.y = acc.y * scale + bf2f(v4.y) * ex;
        acc.z = acc.z * scale + bf2f(v4.z) * ex;
        acc.w = acc.w * scale + bf2f(v4.w) * ex;
        m = mnew;
    }
    const float inv = (s1 > s0) ? 1.0f / den : 0.f;
    float4 o = make_float4(acc.x * inv, acc.y * inv, acc.z * inv, acc.w * inv);
    float4* outp = reinterpret_cast<float4*>(AGG + (size_t)node * 256);
    if (accumulate) {
        const float4 prev = outp[l];
        o.x += prev.x; o.y += prev.y; o.z += prev.z; o.w += prev.w;
    }
    outp[l] = o;
}

// ---------------- residual + LayerNorm ----------------
__global__ __launch_bounds__(256)
void ln_kernel(const float* __restrict__ tmp, const float* __restrict__ hres,
               const float* __restrict__ g, const float* __restrict__ b,
               float* __restrict__ out, int M)
{
    const int gtid = blockIdx.x * blockDim.x + threadIdx.x;
    const int wid = gtid >> 6;
    const int nw = (gridDim.x * blockDim.x) >> 6;
    const int lane = threadIdx.x & 63;
    const float4 gv = reinterpret_cast<const float4*>(g)[lane];
    const float4 bv = reinterpret_cast<const float4*>(b)[lane];
    for (int row = wid; row < M; row += nw) {
        const float4 tv = reinterpret_cast<const float4*>(tmp + (size_t)row * 256)[lane];
        const float4 hv = reinterpret_cast<const float4*>(hres + (size_t)row * 256)[lane];
        float y0 = tv.x + hv.x, y1 = tv.y + hv.y, y2 = tv.z + hv.z, y3 = tv.w + hv.w;
        float ssum = y0 + y1 + y2 + y3;
        #pragma unroll
        for (int off = 32; off; off >>= 1) ssum += __shfl_xor(ssum, off, 64);
        const float mean = ssum * (1.f / 256.f);
        const float d0 = y0 - mean, d1 = y1 - mean, d2 = y2 - mean, d3 = y3 - mean;
        float sq = d0 * d0 + d1 * d1 + d2 * d2 + d3 * d3;
        #pragma unroll
        for (int off = 32; off; off >>= 1) sq += __shfl_xor(sq, off, 64);
        const float inv = rsqrtf(sq * (1.f / 256.f) + 1e-5f);
        float4 o;
        o.x = d0 * inv * gv.x + bv.x;
        o.y = d1 * inv * gv.y + bv.y;
        o.z = d2 * inv * gv.z + bv.z;
        o.w = d3 * inv * gv.w + bv.w;
        reinterpret_cast<float4*>(out + (size_t)row * 256)[lane] = o;
    }
}

extern "C" void kernel_launch(void* const* d_in, const int* in_sizes, int n_in,
                              void* d_out, int out_size, void* d_ws, size_t ws_size,
                              hipStream_t stream)
{
    const float* h    = (const float*)d_in[0];
    const int* src0   = (const int*)d_in[1];
    const int* dst0   = (const int*)d_in[2];
    const int* src1   = (const int*)d_in[3];
    const int* dst1   = (const int*)d_in[4];
    const float* Wk   = (const float*)d_in[5];
    const float* bk   = (const float*)d_in[6];
    const float* Wq   = (const float*)d_in[7];
    const float* bq   = (const float*)d_in[8];
    const float* Wv   = (const float*)d_in[9];
    const float* bv   = (const float*)d_in[10];
    const float* Wa   = (const float*)d_in[11];
    const float* ba   = (const float*)d_in[12];
    const float* lng  = (const float*)d_in[13];
    const float* lnb  = (const float*)d_in[14];
    const float* rel_pri = (const float*)d_in[15];
    const float* rel_att = (const float*)d_in[16];
    const float* rel_msg = (const float*)d_in[17];

    float* ws    = (float*)d_ws;
    float* Q     = ws + OFF_Q;
    unsigned short* KV = (unsigned short*)(ws + OFF_KV);
    float* BBUF  = ws + OFF_BBUF;
    float* BIAS  = ws + OFF_BIAS;
    int* ROWPTR  = (int*)(ws + OFF_ROWPTR);
    int* CURSOR  = (int*)(ws + OFF_CURSOR);
    int* SRCS    = (int*)(ws + OFF_SRCS);
    int* PART    = SRCS;              // first 1024 ints; dead before scatter writes
    unsigned short* BT = (unsigned short*)(ws + OFF_BT);
    float* AGG   = (float*)d_out;     // scratch until final LN
    float* TMP   = ws + OFF_Q;        // GEMM3 output aliases dead Q

    const int NSCAN = (NN + 1023) / 1024;   // 98

    // fused weights -> BBUF/BIAS, then bf16 split-transpose -> BT (BBUF dies)
    build_B_kernel<<<256, 256, 0, stream>>>(Wk, Wq, Wv, bk, bq, bv,
                                            rel_att, rel_msg, BBUF, BIAS);
    conv_B_kernel<<<1536, 256, 0, stream>>>(BBUF, Wa, BT);

    // fused projection: [N,256] x [256,1280] -> q f32 | kr0,vr0,kr1,vr1 bf16
    {
        dim3 grid(1280 / 128, (NN + 127) / 128);
        gemm_mfma<<<grid, 256, 0, stream>>>(h, 256, BT, BIAS, Q, KV, NN, 1.0f);
    }

    // relation 0: CSR + fused aggregation
    zero_kernel<<<128, 256, 0, stream>>>((float4*)CURSOR, (long)NN / 4);
    hist_kernel<<<1024, 256, 0, stream>>>(dst0, CURSOR, EE);
    scan1_kernel<<<NSCAN, 1024, 0, stream>>>(CURSOR, ROWPTR, PART, NN);
    scan2_kernel<<<1, 1024, 0, stream>>>(PART, NSCAN);
    scan3_kernel<<<(NN + 255) / 256, 256, 0, stream>>>(ROWPTR, CURSOR, PART, NN);
    scatter_kernel<<<1024, 256, 0, stream>>>(src0, dst0, CURSOR, SRCS, EE);
    node_agg_kernel<<<NN * 64 / 256, 256, 0, stream>>>(Q, KV, 0, ROWPTR, CURSOR, SRCS,
                                                       rel_pri + 0, AGG, 0);

    // relation 1
    zero_kernel<<<128, 256, 0, stream>>>((float4*)CURSOR, (long)NN / 4);
    hist_kernel<<<1024, 256, 0, stream>>>(dst1, CURSOR, EE);
    scan1_kernel<<<NSCAN, 1024, 0, stream>>>(CURSOR, ROWPTR, PART, NN);
    scan2_kernel<<<1, 1024, 0, stream>>>(PART, NSCAN);
    scan3_kernel<<<(NN + 255) / 256, 256, 0, stream>>>(ROWPTR, CURSOR, PART, NN);
    scatter_kernel<<<1024, 256, 0, stream>>>(src1, dst1, CURSOR, SRCS, EE);
    node_agg_kernel<<<NN * 64 / 256, 256, 0, stream>>>(Q, KV, 512, ROWPTR, CURSOR, SRCS,
                                                       rel_pri + 8, AGG, 1);

    // GEMM3: tmp = 0.5*(agg @ Wa) + ba  (f32 out; bn<256 so KV path never taken)
    {
        dim3 grid(256 / 128, (NN + 127) / 128);
        gemm_mfma<<<grid, 256, 0, stream>>>(AGG, 256, BT + (size_t)1280 * 512, ba,
                                            TMP, KV, NN, 0.5f);
    }
    // residual + layernorm
    ln_kernel<<<2048, 256, 0, stream>>>(TMP, h, lng, lnb, (float*)d_out, NN);
}

// Round 8
// 1063.060 us; speedup vs baseline: 2.2435x; 1.0115x over previous
//
#include <hip/hip_runtime.h>
#include <cstdint>
#include <cstddef>

// HGT layer: N=100000, E=400000/rel, D=256, H=8, DK=32, R=2.
// Round 8:
//  - gemm_mfma: B staged via global_load_lds (width 16) into double-buffered
//    LDS; swizzle moved to per-lane GLOBAL source address (linear LDS dest).
//    A reg-staged with in-kernel f32 -> split-bf16 conversion (3-term split).
//  - Edge phase merged: ONE CSR over 800k edges (rel tag in bit 20 of src),
//    one scan chain, one node_agg with dual online-softmax state, single
//    AGG write (no accumulate pass, Q read once).
//  - ws total 312.78 MB (proven window [311.3, 415.3)).

#define NN 100000
#define EE 400000

static constexpr float INV_SQRT_DK = 0.17677669529663687f; // 1/sqrt(32)

// ---------------- workspace layout (float offsets), total 78,194,496 f = 312.78 MB ----
static constexpr size_t OFF_Q      = 0;                                  // [N][256] f32
static constexpr size_t OFF_KV     = OFF_Q + (size_t)NN * 256;           // [N][1024] bf16
static constexpr size_t OFF_UNION  = OFF_KV + (size_t)NN * 512;
static constexpr size_t OFF_BBUF   = OFF_UNION;                          // [256][1280] f32 (dead after conv_B)
static constexpr size_t OFF_ROWPTR = OFF_UNION;                          // [N] int
static constexpr size_t OFF_CURSOR = OFF_ROWPTR + NN;                    // [N] int
static constexpr size_t OFF_SRCS   = OFF_CURSOR + NN;                    // [2E] int (PART aliases first 1024)
static constexpr size_t OFF_BIAS   = OFF_UNION + 1000000;                // [1280] f32
static constexpr size_t OFF_BT     = OFF_BIAS + 1280;                    // [1536][512] bf16
static constexpr size_t OFF_END    = OFF_BT + (size_t)1536 * 512 / 2;

using bf16x8 = __attribute__((ext_vector_type(8))) __bf16;
using f32x4v = __attribute__((ext_vector_type(4))) float;
using u32x4  = __attribute__((ext_vector_type(4))) unsigned int;

static __device__ inline unsigned int bf_bits(__bf16 b) {
    union { __bf16 b; unsigned short u; } x; x.b = b; return (unsigned int)x.u;
}
static __device__ inline float bf2f(unsigned short u) {
    union { unsigned int u; float f; } x; x.u = ((unsigned int)u) << 16; return x.f;
}

#define GLOAD_LDS16(gsrc, ldst) \
    __builtin_amdgcn_global_load_lds((const __attribute__((address_space(1))) void*)(gsrc), \
                                     (__attribute__((address_space(3))) void*)(ldst), 16, 0, 0)

// ---------------- zero fill ----------------
__global__ __launch_bounds__(256)
void zero_kernel(float4* __restrict__ p, long n4)
{
    const long stride = (long)gridDim.x * blockDim.x;
    for (long i = (long)blockIdx.x * blockDim.x + threadIdx.x; i < n4; i += stride)
        p[i] = make_float4(0.f, 0.f, 0.f, 0.f);
}

// ---------------- fused weight build (f32, into union BBUF) ----------------
__global__ __launch_bounds__(256)
void build_B_kernel(const float* __restrict__ Wk, const float* __restrict__ Wq,
                    const float* __restrict__ Wv,
                    const float* __restrict__ bk, const float* __restrict__ bq,
                    const float* __restrict__ bv,
                    const float* __restrict__ rel_att, const float* __restrict__ rel_msg,
                    float* __restrict__ Bbuf, float* __restrict__ biasbuf)
{
    const int din = blockIdx.x;   // 0..255 (input dim)
    const int t   = threadIdx.x;  // 0..255
    __shared__ float wk[256], wv[256];
    wk[t] = Wk[din * 256 + t];
    wv[t] = Wv[din * 256 + t];
    __syncthreads();
    const int h = t >> 5, e = t & 31;
    Bbuf[(size_t)din * 1280 + t] = Wq[din * 256 + t];
    #pragma unroll
    for (int r = 0; r < 2; ++r) {
        const float* ra = rel_att + (size_t)((r * 8 + h) * 32) * 32 + e;
        const float* rm = rel_msg + (size_t)((r * 8 + h) * 32) * 32 + e;
        float sa = 0.f, sm = 0.f;
        #pragma unroll
        for (int dd = 0; dd < 32; ++dd) {
            sa = fmaf(wk[h * 32 + dd], ra[dd * 32], sa);
            sm = fmaf(wv[h * 32 + dd], rm[dd * 32], sm);
        }
        Bbuf[(size_t)din * 1280 + 256 + r * 512 + t]       = sa;
        Bbuf[(size_t)din * 1280 + 256 + r * 512 + 256 + t] = sm;
    }
    if (din == 0) {
        biasbuf[t] = bq[t];
        #pragma unroll
        for (int r = 0; r < 2; ++r) {
            float sa = 0.f, sm = 0.f;
            #pragma unroll
            for (int dd = 0; dd < 32; ++dd) {
                sa = fmaf(bk[h * 32 + dd], rel_att[(size_t)((r * 8 + h) * 32 + dd) * 32 + e], sa);
                sm = fmaf(bv[h * 32 + dd], rel_msg[(size_t)((r * 8 + h) * 32 + dd) * 32 + e], sm);
            }
            biasbuf[256 + r * 512 + t]       = sa;
            biasbuf[256 + r * 512 + 256 + t] = sm;
        }
    }
}

// BBUF [256][1280] + Wa [256][256] -> BT [1536][512] bf16 (n-major; hi|lo)
__global__ __launch_bounds__(256)
void conv_B_kernel(const float* __restrict__ Bbuf, const float* __restrict__ Wa,
                   unsigned short* __restrict__ BT)
{
    const int n = blockIdx.x;    // 0..1535
    const int k = threadIdx.x;   // 0..255
    const float v = (n < 1280) ? Bbuf[(size_t)k * 1280 + n]
                               : Wa[(size_t)k * 256 + (n - 1280)];
    __bf16 hi = (__bf16)v;
    __bf16 lo = (__bf16)(v - (float)hi);
    BT[(size_t)n * 512 + k]       = (unsigned short)bf_bits(hi);
    BT[(size_t)n * 512 + 256 + k] = (unsigned short)bf_bits(lo);
}

// ---------------- split-bf16 MFMA GEMM ----------------
// A reg-staged + converted; B via global_load_lds into double-buffered LDS
// (linear dest, inverse-swizzled per-lane global source, swizzled reads).
__global__ __launch_bounds__(256)
void gemm_mfma(const float* __restrict__ A, int lda,
               const unsigned short* __restrict__ BT,
               const float* __restrict__ bias,
               float* __restrict__ Qout, unsigned short* __restrict__ KVout,
               int M, float alpha)
{
    __shared__ __align__(16) unsigned short AsB[128 * 64];        // 16 KB
    __shared__ __align__(16) unsigned short BsB[2][128 * 64];     // 32 KB dbuf
    const int tid = threadIdx.x;
    const int bn = blockIdx.x * 128;
    const int bm = blockIdx.y * 128;
    const int wid = tid >> 6;
    const int l   = tid & 63;
    const int wm  = (wid >> 1) * 64;
    const int wn  = (wid & 1) * 64;
    const int l15 = l & 15;
    const int k8  = (l >> 4) * 8;

    f32x4v acc[4][4];
    #pragma unroll
    for (int i = 0; i < 4; ++i)
        #pragma unroll
        for (int j = 0; j < 4; ++j)
            acc[i][j] = (f32x4v){0.f, 0.f, 0.f, 0.f};

    float4 rA[2][2];

    auto g_load_A = [&](int kb) {
        #pragma unroll
        for (int it = 0; it < 2; ++it) {
            const int s = it * 256 + tid;
            const int row = s >> 2, c8 = (s & 3) * 8;
            const float* base = A + (size_t)(bm + row) * lda + kb * 32 + c8;
            const bool ok = (bm + row) < M;
            rA[it][0] = ok ? *reinterpret_cast<const float4*>(base)     : make_float4(0,0,0,0);
            rA[it][1] = ok ? *reinterpret_cast<const float4*>(base + 4) : make_float4(0,0,0,0);
        }
    };
    auto stage_B = [&](int kb, int buf) {
        char* lbase = reinterpret_cast<char*>(&BsB[buf][0]);
        #pragma unroll
        for (int it = 0; it < 4; ++it) {
            const int s = it * 256 + tid;
            const int row = s >> 3, q = s & 7;
            const int qq = q ^ (row & 7);   // inverse swizzle on global source
            const char* gsrc = reinterpret_cast<const char*>(BT) + (size_t)(bn + row) * 1024
                               + ((qq < 4) ? (kb * 64 + qq * 16) : (512 + kb * 64 + (qq - 4) * 16));
            GLOAD_LDS16(gsrc, lbase + s * 16);
        }
    };

    stage_B(0, 0);
    g_load_A(0);

    for (int kb = 0; kb < 8; ++kb) {
        __syncthreads();   // drains vmcnt: B(kb) in LDS, A(kb) regs ready; prev MFMA done
        // A: convert f32 -> hi/lo bf16, swizzled ds_write
        #pragma unroll
        for (int it = 0; it < 2; ++it) {
            const int s = it * 256 + tid;
            const int row = s >> 2, c8 = (s & 3) * 8;
            float vv[8] = {rA[it][0].x, rA[it][0].y, rA[it][0].z, rA[it][0].w,
                           rA[it][1].x, rA[it][1].y, rA[it][1].z, rA[it][1].w};
            unsigned int hw[4], lw[4];
            #pragma unroll
            for (int j = 0; j < 4; ++j) {
                const __bf16 h0 = (__bf16)vv[2*j],  h1 = (__bf16)vv[2*j+1];
                const float  r0 = vv[2*j] - (float)h0, r1 = vv[2*j+1] - (float)h1;
                const __bf16 l0 = (__bf16)r0, l1 = (__bf16)r1;
                hw[j] = bf_bits(h0) | (bf_bits(h1) << 16);
                lw[j] = bf_bits(l0) | (bf_bits(l1) << 16);
            }
            const int swz = (row & 7) << 4;
            char* basep = reinterpret_cast<char*>(AsB);
            *reinterpret_cast<u32x4*>(basep + ((row * 128 +      c8 * 2) ^ swz)) = (u32x4){hw[0],hw[1],hw[2],hw[3]};
            *reinterpret_cast<u32x4*>(basep + ((row * 128 + 64 + c8 * 2) ^ swz)) = (u32x4){lw[0],lw[1],lw[2],lw[3]};
        }
        __syncthreads();
        if (kb < 7) { stage_B(kb + 1, (kb + 1) & 1); g_load_A(kb + 1); }

        const char* bbase = reinterpret_cast<const char*>(&BsB[kb & 1][0]);
        #pragma unroll
        for (int term = 0; term < 3; ++term) {
            const int apart = (term == 1) ? 64 : 0;
            const int bpart = (term == 2) ? 64 : 0;
            bf16x8 af[4], bfr[4];
            #pragma unroll
            for (int i = 0; i < 4; ++i) {
                const int arow = wm + i * 16 + l15;
                af[i]  = *reinterpret_cast<const bf16x8*>(reinterpret_cast<const char*>(AsB)
                           + ((arow * 128 + apart + k8 * 2) ^ ((arow & 7) << 4)));
                const int brow = wn + i * 16 + l15;
                bfr[i] = *reinterpret_cast<const bf16x8*>(bbase
                           + ((brow * 128 + bpart + k8 * 2) ^ ((brow & 7) << 4)));
            }
            #pragma unroll
            for (int i = 0; i < 4; ++i)
                #pragma unroll
                for (int j = 0; j < 4; ++j)
                    acc[i][j] = __builtin_amdgcn_mfma_f32_16x16x32_bf16(af[i], bfr[j], acc[i][j], 0, 0, 0);
        }
    }

    // epilogue: C/D layout col=lane&15, row=(lane>>4)*4+reg (m89-verified)
    const bool q_seg = (bn < 256);
    #pragma unroll
    for (int i = 0; i < 4; ++i) {
        const int rbase = bm + wm + i * 16 + (l >> 4) * 4;
        #pragma unroll
        for (int j = 0; j < 4; ++j) {
            const int col = bn + wn + j * 16 + l15;
            const float bcol = bias[col];
            #pragma unroll
            for (int r = 0; r < 4; ++r) {
                const int row = rbase + r;
                if (row < M) {
                    const float o = alpha * acc[i][j][r] + bcol;
                    if (q_seg)
                        Qout[(size_t)row * 256 + col] = o;
                    else
                        KVout[(size_t)row * 1024 + (col - 256)] = (unsigned short)bf_bits((__bf16)o);
                }
            }
        }
    }
}

// ---------------- combined CSR build (both relations) ----------------
__global__ __launch_bounds__(256)
void hist2_kernel(const int* __restrict__ dst0, const int* __restrict__ dst1,
                  int* __restrict__ deg)
{
    const int stride = gridDim.x * blockDim.x;
    for (int i = blockIdx.x * blockDim.x + threadIdx.x; i < 2 * EE; i += stride) {
        const int d = (i < EE) ? dst0[i] : dst1[i - EE];
        atomicAdd(&deg[d], 1);
    }
}

__global__ __launch_bounds__(1024)
void scan1_kernel(const int* __restrict__ deg, int* __restrict__ rowptr,
                  int* __restrict__ part, int n)
{
    __shared__ int sm[1024];
    const int tid = threadIdx.x;
    const int i = blockIdx.x * 1024 + tid;
    const int v = (i < n) ? deg[i] : 0;
    sm[tid] = v;
    __syncthreads();
    for (int off = 1; off < 1024; off <<= 1) {
        int add = (tid >= off) ? sm[tid - off] : 0;
        __syncthreads();
        sm[tid] += add;
        __syncthreads();
    }
    if (i < n) rowptr[i] = sm[tid] - v;
    if (tid == 1023) part[blockIdx.x] = sm[1023];
}

__global__ __launch_bounds__(1024)
void scan2_kernel(int* __restrict__ part, int np)
{
    __shared__ int sm[1024];
    const int tid = threadIdx.x;
    const int v = (tid < np) ? part[tid] : 0;
    sm[tid] = v;
    __syncthreads();
    for (int off = 1; off < 1024; off <<= 1) {
        int add = (tid >= off) ? sm[tid - off] : 0;
        __syncthreads();
        sm[tid] += add;
        __syncthreads();
    }
    if (tid < np) part[tid] = sm[tid] - v;
}

__global__ __launch_bounds__(256)
void scan3_kernel(int* __restrict__ rowptr, int* __restrict__ cursor,
                  const int* __restrict__ part, int n)
{
    const int i = blockIdx.x * 256 + threadIdx.x;
    if (i < n) {
        const int r = rowptr[i] + part[i >> 10];
        rowptr[i] = r;
        cursor[i] = r;
    }
}

// scatter both relations; srcs entry = src | (rel << 20)
__global__ __launch_bounds__(256)
void scatter2_kernel(const int* __restrict__ src0, const int* __restrict__ dst0,
                     const int* __restrict__ src1, const int* __restrict__ dst1,
                     int* __restrict__ cursor, int* __restrict__ srcs)
{
    const int stride = gridDim.x * blockDim.x;
    for (int i = blockIdx.x * blockDim.x + threadIdx.x; i < 2 * EE; i += stride) {
        const int rel = (i >= EE);
        const int e = rel ? (i - EE) : i;
        const int d  = rel ? dst1[e] : dst0[e];
        const int sv = (rel ? src1[e] : src0[e]) | (rel << 20);
        int pos = atomicAdd(&cursor[d], 1);
        srcs[pos] = sv;
    }
}

// ---------------- merged dual-relation online-softmax aggregation ----------------
// one wave per node; lane l: head h=l>>3, owns dims [4l,4l+4).
// rel tag is wave-uniform per edge -> uniform branch.
__global__ __launch_bounds__(256)
void node_agg2_kernel(const float* __restrict__ Q, const unsigned short* __restrict__ KV,
                      const int* __restrict__ rowptr, const int* __restrict__ endptr,
                      const int* __restrict__ srcs,
                      const float* __restrict__ rel_pri,  // [16]
                      float* __restrict__ AGG)
{
    const int node = (blockIdx.x * blockDim.x + threadIdx.x) >> 6;
    if (node >= NN) return;
    const int l = threadIdx.x & 63;
    const int h = l >> 3;
    const float4 q4 = reinterpret_cast<const float4*>(Q + (size_t)node * 256)[l];
    const float pr0 = rel_pri[h] * INV_SQRT_DK;
    const float pr1 = rel_pri[8 + h] * INV_SQRT_DK;
    const int s0 = rowptr[node];
    const int s1 = endptr[node];
    float m0 = -3.0e38f, m1 = -3.0e38f, den0 = 0.f, den1 = 0.f;
    float4 a0 = make_float4(0.f, 0.f, 0.f, 0.f);
    float4 a1 = make_float4(0.f, 0.f, 0.f, 0.f);
    for (int i = s0; i < s1; ++i) {
        const int p = srcs[i];
        const int s = p & 0xFFFFF;
        const int rel = p >> 20;
        const unsigned short* kv = KV + (size_t)s * 1024 + (rel << 9);
        const ushort4 k4 = *reinterpret_cast<const ushort4*>(kv + l * 4);
        float t = q4.x * bf2f(k4.x) + q4.y * bf2f(k4.y) + q4.z * bf2f(k4.z) + q4.w * bf2f(k4.w);
        t += __shfl_xor(t, 1, 64);
        t += __shfl_xor(t, 2, 64);
        t += __shfl_xor(t, 4, 64);
        const ushort4 v4 = *reinterpret_cast<const ushort4*>(kv + 256 + l * 4);
        const float vx = bf2f(v4.x), vy = bf2f(v4.y), vz = bf2f(v4.z), vw = bf2f(v4.w);
        if (rel == 0) {
            const float sc = t * pr0;
            const float mn = fmaxf(m0, sc);
            const float scale = __expf(m0 - mn);
            const float ex = __expf(sc - mn);
            den0 = den0 * scale + ex;
            a0.x = a0.x * scale + vx * ex;
            a0.y = a0.y * scale + vy * ex;
            a0.z = a0.z * scale + vz * ex;
            a0.w = a0.w * scale + vw * ex;
            m0 = mn;
        } else {
            const float sc = t * pr1;
            const float mn = fmaxf(m1, sc);
            const float scale = __expf(m1 - mn);
            const float ex = __expf(sc - mn);
            den1 = den1 * scale + ex;
            a1.x = a1.x * scale + vx * ex;
            a1.y = a1.y * scale + vy * ex;
            a1.z = a1.z * scale + vz * ex;
            a1.w = a1.w * scale + vw * ex;
            m1 = mn;
        }
    }
    const float i0 = (den0 > 0.f) ? 1.0f / den0 : 0.f;
    const float i1 = (den1 > 0.f) ? 1.0f / den1 : 0.f;
    float4 o;
    o.x = a0.x * i0 + a1.x * i1;
    o.y = a0.y * i0 + a1.y * i1;
    o.z = a0.z * i0 + a1.z * i1;
    o.w = a0.w * i0 + a1.w * i1;
    reinterpret_cast<float4*>(AGG + (size_t)node * 256)[l] = o;
}

// ---------------- residual + LayerNorm ----------------
__global__ __launch_bounds__(256)
void ln_kernel(const float* __restrict__ tmp, const float* __restrict__ hres,
               const float* __restrict__ g, const float* __restrict__ b,
               float* __restrict__ out, int M)
{
    const int gtid = blockIdx.x * blockDim.x + threadIdx.x;
    const int wid = gtid >> 6;
    const int nw = (gridDim.x * blockDim.x) >> 6;
    const int lane = threadIdx.x & 63;
    const float4 gv = reinterpret_cast<const float4*>(g)[lane];
    const float4 bv = reinterpret_cast<const float4*>(b)[lane];
    for (int row = wid; row < M; row += nw) {
        const float4 tv = reinterpret_cast<const float4*>(tmp + (size_t)row * 256)[lane];
        const float4 hv = reinterpret_cast<const float4*>(hres + (size_t)row * 256)[lane];
        float y0 = tv.x + hv.x, y1 = tv.y + hv.y, y2 = tv.z + hv.z, y3 = tv.w + hv.w;
        float ssum = y0 + y1 + y2 + y3;
        #pragma unroll
        for (int off = 32; off; off >>= 1) ssum += __shfl_xor(ssum, off, 64);
        const float mean = ssum * (1.f / 256.f);
        const float d0 = y0 - mean, d1 = y1 - mean, d2 = y2 - mean, d3 = y3 - mean;
        float sq = d0 * d0 + d1 * d1 + d2 * d2 + d3 * d3;
        #pragma unroll
        for (int off = 32; off; off >>= 1) sq += __shfl_xor(sq, off, 64);
        const float inv = rsqrtf(sq * (1.f / 256.f) + 1e-5f);
        float4 o;
        o.x = d0 * inv * gv.x + bv.x;
        o.y = d1 * inv * gv.y + bv.y;
        o.z = d2 * inv * gv.z + bv.z;
        o.w = d3 * inv * gv.w + bv.w;
        reinterpret_cast<float4*>(out + (size_t)row * 256)[lane] = o;
    }
}

extern "C" void kernel_launch(void* const* d_in, const int* in_sizes, int n_in,
                              void* d_out, int out_size, void* d_ws, size_t ws_size,
                              hipStream_t stream)
{
    const float* h    = (const float*)d_in[0];
    const int* src0   = (const int*)d_in[1];
    const int* dst0   = (const int*)d_in[2];
    const int* src1   = (const int*)d_in[3];
    const int* dst1   = (const int*)d_in[4];
    const float* Wk   = (const float*)d_in[5];
    const float* bk   = (const float*)d_in[6];
    const float* Wq   = (const float*)d_in[7];
    const float* bq   = (const float*)d_in[8];
    const float* Wv   = (const float*)d_in[9];
    const float* bv   = (const float*)d_in[10];
    const float* Wa   = (const float*)d_in[11];
    const float* ba   = (const float*)d_in[12];
    const float* lng  = (const float*)d_in[13];
    const float* lnb  = (const float*)d_in[14];
    const float* rel_pri = (const float*)d_in[15];
    const float* rel_att = (const float*)d_in[16];
    const float* rel_msg = (const float*)d_in[17];

    float* ws    = (float*)d_ws;
    float* Q     = ws + OFF_Q;
    unsigned short* KV = (unsigned short*)(ws + OFF_KV);
    float* BBUF  = ws + OFF_BBUF;
    float* BIAS  = ws + OFF_BIAS;
    int* ROWPTR  = (int*)(ws + OFF_ROWPTR);
    int* CURSOR  = (int*)(ws + OFF_CURSOR);
    int* SRCS    = (int*)(ws + OFF_SRCS);
    int* PART    = SRCS;              // first 1024 ints; dead before scatter writes
    unsigned short* BT = (unsigned short*)(ws + OFF_BT);
    float* AGG   = (float*)d_out;     // scratch until final LN
    float* TMP   = ws + OFF_Q;        // GEMM3 output aliases dead Q

    const int NSCAN = (NN + 1023) / 1024;   // 98

    // fused weights -> BBUF/BIAS, then bf16 split-transpose -> BT (BBUF dies)
    build_B_kernel<<<256, 256, 0, stream>>>(Wk, Wq, Wv, bk, bq, bv,
                                            rel_att, rel_msg, BBUF, BIAS);
    conv_B_kernel<<<1536, 256, 0, stream>>>(BBUF, Wa, BT);

    // fused projection: [N,256] x [256,1280] -> q f32 | kr0,vr0,kr1,vr1 bf16
    {
        dim3 grid(1280 / 128, (NN + 127) / 128);
        gemm_mfma<<<grid, 256, 0, stream>>>(h, 256, BT, BIAS, Q, KV, NN, 1.0f);
    }

    // combined CSR over both relations
    zero_kernel<<<128, 256, 0, stream>>>((float4*)CURSOR, (long)NN / 4);
    hist2_kernel<<<1024, 256, 0, stream>>>(dst0, dst1, CURSOR);
    scan1_kernel<<<NSCAN, 1024, 0, stream>>>(CURSOR, ROWPTR, PART, NN);
    scan2_kernel<<<1, 1024, 0, stream>>>(PART, NSCAN);
    scan3_kernel<<<(NN + 255) / 256, 256, 0, stream>>>(ROWPTR, CURSOR, PART, NN);
    scatter2_kernel<<<1024, 256, 0, stream>>>(src0, dst0, src1, dst1, CURSOR, SRCS);

    // merged aggregation (single AGG write)
    node_agg2_kernel<<<NN * 64 / 256, 256, 0, stream>>>(Q, KV, ROWPTR, CURSOR, SRCS,
                                                        rel_pri, AGG);

    // GEMM3: tmp = 0.5*(agg @ Wa) + ba  (bn<256 -> f32 Qout path)
    {
        dim3 grid(256 / 128, (NN + 127) / 128);
        gemm_mfma<<<grid, 256, 0, stream>>>(AGG, 256, BT + (size_t)1280 * 512, ba,
                                            TMP, KV, NN, 0.5f);
    }
    // residual + layernorm
    ln_kernel<<<2048, 256, 0, stream>>>(TMP, h, lng, lnb, (float*)d_out, NN);
}